// Round 5
// baseline (567.323 us; speedup 1.0000x reference)
//
#include <hip/hip_runtime.h>
#include <hip/hip_bf16.h>
#include <math.h>

#define VERY_NEG (-1e30f)

// B=128, S=256, H=256, C=20000, NODES=25000, A=8, NH=8, d=32, FF=1024
constexpr int Bc = 128, Sc = 256, Hc = 256, Cc = 20000, Ac = 8, NHc = 8, DHc = 32, FFc = 1024;
constexpr int Mc = Bc * Sc;  // 32768 rows
constexpr int Rc = Cc * Ac;  // 160000 dag rows

typedef __attribute__((ext_vector_type(8))) short short8;
typedef __attribute__((ext_vector_type(4))) float floatx4;

static __device__ __forceinline__ unsigned short f2bf(float f) {
  union { float f; unsigned u; } v; v.f = f;
  unsigned r = v.u + 0x7FFF + ((v.u >> 16) & 1);   // RNE
  return (unsigned short)(r >> 16);
}
static __device__ __forceinline__ unsigned pack2(float lo, float hi) {
  return (unsigned)f2bf(lo) | ((unsigned)f2bf(hi) << 16);
}
static __device__ __forceinline__ float bf2f(unsigned short u) {
  union { unsigned u; float f; } v; v.u = ((unsigned)u) << 16; return v.f;
}

// async global->LDS, 16B per lane; lane i lands at base + i*16.
static __device__ __forceinline__ void glds16(const unsigned short* g,
                                              unsigned short* l) {
  __builtin_amdgcn_global_load_lds(
      (const __attribute__((address_space(1))) void*)g,
      (__attribute__((address_space(3))) void*)l, 16, 0, 0);
}

// ---------------------------------------------------------------------------
// Per-layer weight prep, one launch: wq/wk/wv -> qkvT[768][256],
// wo -> woT[256][256], fw1 -> fw1T[1024][256], fw2 -> fw2T[256][1024].
// ---------------------------------------------------------------------------
__global__ __launch_bounds__(256) void prep_weights(
    const float* __restrict__ wq, const float* __restrict__ wk,
    const float* __restrict__ wv, const float* __restrict__ wo,
    const float* __restrict__ fw1, const float* __restrict__ fw2,
    unsigned short* __restrict__ qkvT, unsigned short* __restrict__ woT,
    unsigned short* __restrict__ fw1T, unsigned short* __restrict__ fw2T) {
  int gid = blockIdx.x * 256 + threadIdx.x;
  if (gid < 196608) {
    int which = gid >> 16, rem = gid & 65535;
    int n = rem >> 8, k = rem & 255;
    const float* w = which == 0 ? wq : (which == 1 ? wk : wv);
    qkvT[gid] = f2bf(w[k * 256 + n]);
  } else if (gid < 262144) {
    int rem = gid - 196608;
    int n = rem >> 8, k = rem & 255;
    woT[rem] = f2bf(wo[k * 256 + n]);
  } else if (gid < 524288) {
    int rem = gid - 262144;
    int n = rem >> 8, k = rem & 255;   // n 0..1023
    fw1T[rem] = f2bf(fw1[k * 1024 + n]);
  } else {
    int rem = gid - 524288;
    int n = rem >> 10, k = rem & 1023; // n 0..255
    fw2T[rem] = f2bf(fw2[k * 256 + n]);
  }
}

// ---------------------------------------------------------------------------
// bf16 MFMA GEMM, glds staging, BK=64, XOR-swizzled unpadded LDS [128][64].
// XCD-aware bijective blockIdx swizzle (all launches have nwg%8==0).
// OUT: 0 fp32->Cf; 1 bf16->C2; 2 both; 3 bf16 QKV split (col>>8 buffer).
// ---------------------------------------------------------------------------
template <int K, bool BIAS, bool RELU, bool RESID, int OUT>
__global__ __launch_bounds__(256) void gemm_mfma(
    const unsigned short* __restrict__ A, const unsigned short* __restrict__ Bt,
    const float* __restrict__ bias, const float* __restrict__ resid,
    float* __restrict__ Cf, unsigned short* __restrict__ C2, int N) {
  __shared__ unsigned short As[128 * 64];
  __shared__ unsigned short Bs[128 * 64];
  const int tid = threadIdx.x;
  const int nwg = gridDim.x * gridDim.y;
  const int bid0 = blockIdx.y * gridDim.x + blockIdx.x;
  const int swz = (bid0 & 7) * (nwg >> 3) + (bid0 >> 3);
  const int rowBase = (swz / gridDim.x) * 128;
  const int colBase = (swz % gridDim.x) * 128;
  const int wave = tid >> 6, lane = tid & 63;
  const int wm = wave >> 1, wn = wave & 1;
  const int quad = lane >> 4, l15 = lane & 15;
  const int s8 = (((lane & 7) ^ (lane >> 3)) << 3);  // swizzled global chunk
  const int rs0 = (wave << 5) + (lane >> 3);         // staged row base
  const int swzf = l15 & 7;

  floatx4 acc[4][4];
#pragma unroll
  for (int mt = 0; mt < 4; ++mt)
#pragma unroll
    for (int nt = 0; nt < 4; ++nt) acc[mt][nt] = (floatx4){0.f, 0.f, 0.f, 0.f};

  for (int k0 = 0; k0 < K; k0 += 64) {
#pragma unroll
    for (int i = 0; i < 4; ++i) {
      int r = rs0 + (i << 3);
      int lb = wave * 2048 + i * 512;
      glds16(A + (size_t)(rowBase + r) * K + k0 + s8, &As[lb]);
      glds16(Bt + (size_t)(colBase + r) * K + k0 + s8, &Bs[lb]);
    }
    __syncthreads();
#pragma unroll
    for (int kk = 0; kk < 2; ++kk) {
      short8 af[4], bfr[4];
#pragma unroll
      for (int mt = 0; mt < 4; ++mt)
        af[mt] = *(const short8*)&As[(wm * 64 + mt * 16 + l15) * 64 +
                                     ((((kk << 2) | quad) ^ swzf) << 3)];
#pragma unroll
      for (int nt = 0; nt < 4; ++nt)
        bfr[nt] = *(const short8*)&Bs[(wn * 64 + nt * 16 + l15) * 64 +
                                      ((((kk << 2) | quad) ^ swzf) << 3)];
#pragma unroll
      for (int mt = 0; mt < 4; ++mt)
#pragma unroll
        for (int nt = 0; nt < 4; ++nt)
          acc[mt][nt] = __builtin_amdgcn_mfma_f32_16x16x32_bf16(
              af[mt], bfr[nt], acc[mt][nt], 0, 0, 0);
    }
    __syncthreads();
  }

#pragma unroll
  for (int mt = 0; mt < 4; ++mt) {
#pragma unroll
    for (int nt = 0; nt < 4; ++nt) {
      int col = colBase + wn * 64 + nt * 16 + l15;
      float bz = BIAS ? bias[col] : 0.f;
#pragma unroll
      for (int i = 0; i < 4; ++i) {
        int row = rowBase + wm * 64 + mt * 16 + quad * 4 + i;
        float v = acc[mt][nt][i];
        if (BIAS) v += bz;
        if (RELU) v = fmaxf(v, 0.f);
        if (RESID) v += resid[(size_t)row * N + col];
        if (OUT == 0) {
          Cf[(size_t)row * N + col] = v;
        } else if (OUT == 1) {
          C2[(size_t)row * N + col] = f2bf(v);
        } else if (OUT == 2) {
          Cf[(size_t)row * N + col] = v;
          C2[(size_t)row * N + col] = f2bf(v);
        } else {  // QKV split
          C2[(size_t)(col >> 8) * 16777216 + (size_t)row * 256 + (col & 255)] =
              f2bf(v);
        }
      }
    }
  }
}

// ---------------------------------------------------------------------------
// Fused FFN: out = relu(x@W1+b1)@W2 + b2 + resid, hidden never leaves LDS.
// Grid 256 blocks (1/CU), 128 rows each. LDS: Xs 64K + Ws 32K + Hs 32K=128K.
// Per nb (8 hidden 128-col blocks): stage W1 (2 halves), MFMA h, relu+b1,
// pack h into swizzled Hs, stage W2 slice into Ws, MFMA into persistent
// acc2[4][8] (y 128x256 fp32). Saves 134MB HBM round-trip per encoder.
// ---------------------------------------------------------------------------
__global__ __launch_bounds__(256, 1) void ffn_fused(
    const unsigned short* __restrict__ A, const unsigned short* __restrict__ w1T,
    const unsigned short* __restrict__ w2T, const float* __restrict__ b1,
    const float* __restrict__ b2, const float* __restrict__ resid,
    float* __restrict__ outC) {
  __shared__ unsigned short Xs[4][8192];  // x tile, 4 k-chunks [128][64]
  __shared__ unsigned short Ws[2][8192];  // W1 half [2][128][64] / W2 [256][64]
  __shared__ unsigned short Hs[2][8192];  // h tile, 2 k-chunks [128][64]
  const int tid = threadIdx.x;
  const int wave = tid >> 6, lane = tid & 63;
  const int wm = wave >> 1, wn = wave & 1;
  const int quad = lane >> 4, l15 = lane & 15;
  const int s8 = (((lane & 7) ^ (lane >> 3)) << 3);
  const int rs0 = (wave << 5) + (lane >> 3);   // [128][64] staging rows
  const int rs0b = (wave << 6) + (lane >> 3);  // [256][64] staging rows
  const int swzf = l15 & 15 & 7;
  const int rowBase = blockIdx.x * 128;

  // stage x tile once (completion guaranteed by first __syncthreads below)
#pragma unroll
  for (int kc = 0; kc < 4; ++kc)
#pragma unroll
    for (int i = 0; i < 4; ++i) {
      int r = rs0 + (i << 3);
      glds16(A + (size_t)(rowBase + r) * 256 + kc * 64 + s8,
             &Xs[kc][wave * 2048 + i * 512]);
    }

  floatx4 acc2[4][8];
#pragma unroll
  for (int mt = 0; mt < 4; ++mt)
#pragma unroll
    for (int nt = 0; nt < 8; ++nt) acc2[mt][nt] = (floatx4){0.f, 0.f, 0.f, 0.f};

  for (int nb = 0; nb < 8; ++nb) {
    floatx4 hacc[4][4];
#pragma unroll
    for (int mt = 0; mt < 4; ++mt)
#pragma unroll
      for (int nt = 0; nt < 4; ++nt) hacc[mt][nt] = (floatx4){0.f, 0.f, 0.f, 0.f};

    // ---- stage 1: h = x @ W1[:, nb*128:+128], K=256 in 2 halves ----
#pragma unroll
    for (int hf = 0; hf < 2; ++hf) {
#pragma unroll
      for (int kc = 0; kc < 2; ++kc)
#pragma unroll
        for (int i = 0; i < 4; ++i) {
          int r = rs0 + (i << 3);
          glds16(w1T + (size_t)(nb * 128 + r) * 256 + (hf * 2 + kc) * 64 + s8,
                 &Ws[kc][wave * 2048 + i * 512]);
        }
      __syncthreads();
#pragma unroll
      for (int kc = 0; kc < 2; ++kc) {
        int kg = hf * 2 + kc;
#pragma unroll
        for (int kk = 0; kk < 2; ++kk) {
          short8 af[4], bfr[4];
#pragma unroll
          for (int mt = 0; mt < 4; ++mt)
            af[mt] = *(const short8*)&Xs[kg][(wm * 64 + mt * 16 + l15) * 64 +
                                            ((((kk << 2) | quad) ^ swzf) << 3)];
#pragma unroll
          for (int nt = 0; nt < 4; ++nt)
            bfr[nt] = *(const short8*)&Ws[kc][(wn * 64 + nt * 16 + l15) * 64 +
                                             ((((kk << 2) | quad) ^ swzf) << 3)];
#pragma unroll
          for (int mt = 0; mt < 4; ++mt)
#pragma unroll
            for (int nt = 0; nt < 4; ++nt)
              hacc[mt][nt] = __builtin_amdgcn_mfma_f32_16x16x32_bf16(
                  af[mt], bfr[nt], hacc[mt][nt], 0, 0, 0);
        }
      }
      __syncthreads();  // all waves done reading Ws -> safe to restage
    }

    // ---- relu+b1, pack h into swizzled Hs; stage W2 kc2=0 concurrently ----
    float b1v[4];
#pragma unroll
    for (int nt = 0; nt < 4; ++nt)
      b1v[nt] = b1[nb * 128 + wn * 64 + nt * 16 + l15];
#pragma unroll
    for (int mt = 0; mt < 4; ++mt)
#pragma unroll
      for (int nt = 0; nt < 4; ++nt) {
        int nh = wn * 64 + nt * 16 + l15;
        int kc2 = nh >> 6, c6 = nh & 63;
#pragma unroll
        for (int i = 0; i < 4; ++i) {
          int row = wm * 64 + mt * 16 + quad * 4 + i;
          float hv = fmaxf(hacc[mt][nt][i] + b1v[nt], 0.f);
          Hs[kc2][row * 64 + ((((c6 >> 3) ^ (row & 7)) << 3) | (c6 & 7))] =
              f2bf(hv);
        }
      }
#pragma unroll
    for (int i = 0; i < 8; ++i) {  // W2 [256 out][64 k], kc2=0
      int r = rs0b + (i << 3);
      glds16(w2T + (size_t)r * 1024 + nb * 128 + s8,
             &Ws[0][wave * 4096 + i * 512]);
    }
    __syncthreads();

    // ---- stage 2: y += h @ W2[nb*128:+128, :], 2 k-chunks ----
#pragma unroll
    for (int kc2 = 0; kc2 < 2; ++kc2) {
      if (kc2 == 1) {
        __syncthreads();  // done reading Ws(kc2=0)
#pragma unroll
        for (int i = 0; i < 8; ++i) {
          int r = rs0b + (i << 3);
          glds16(w2T + (size_t)r * 1024 + nb * 128 + 64 + s8,
                 &Ws[0][wave * 4096 + i * 512]);
        }
        __syncthreads();
      }
#pragma unroll
      for (int kk = 0; kk < 2; ++kk) {
        short8 pf[4], bfr2[8];
#pragma unroll
        for (int mt = 0; mt < 4; ++mt)
          pf[mt] = *(const short8*)&Hs[kc2][(wm * 64 + mt * 16 + l15) * 64 +
                                           ((((kk << 2) | quad) ^ swzf) << 3)];
        const unsigned short* W2f = &Ws[0][0];
#pragma unroll
        for (int nt = 0; nt < 8; ++nt)
          bfr2[nt] = *(const short8*)&W2f[(wn * 128 + nt * 16 + l15) * 64 +
                                          ((((kk << 2) | quad) ^ swzf) << 3)];
#pragma unroll
        for (int mt = 0; mt < 4; ++mt)
#pragma unroll
          for (int nt = 0; nt < 8; ++nt)
            acc2[mt][nt] = __builtin_amdgcn_mfma_f32_16x16x32_bf16(
                pf[mt], bfr2[nt], acc2[mt][nt], 0, 0, 0);
      }
    }
    __syncthreads();  // done reading Ws & Hs before next nb overwrites
  }

  // ---- epilogue: + b2 + resid -> fp32 out ----
#pragma unroll
  for (int mt = 0; mt < 4; ++mt)
#pragma unroll
    for (int nt = 0; nt < 8; ++nt) {
      int col = wn * 128 + nt * 16 + l15;
      float bz = b2[col];
#pragma unroll
      for (int i = 0; i < 4; ++i) {
        int row = rowBase + wm * 64 + mt * 16 + quad * 4 + i;
        outC[(size_t)row * 256 + col] =
            acc2[mt][nt][i] + bz + resid[(size_t)row * 256 + col];
      }
    }
}

// ---------------------------------------------------------------------------
// DAG stage 0a: embed_init_w [25001][256] fp32 -> emb16 [25088][256] bf16
// ---------------------------------------------------------------------------
__global__ __launch_bounds__(256) void cvt_emb16(
    const float* __restrict__ emb, unsigned short* __restrict__ e16) {
  int gid = blockIdx.x * 256 + threadIdx.x;  // 802816 threads, 8 elems each
  int base = gid * 8;
  int row = base >> 8;
  uint4 o;
  if (row < 25001) {
    float4 a = *(const float4*)(emb + base);
    float4 b = *(const float4*)(emb + base + 4);
    o.x = pack2(a.x, a.y); o.y = pack2(a.z, a.w);
    o.z = pack2(b.x, b.y); o.w = pack2(b.z, b.w);
  } else {
    o = (uint4){0u, 0u, 0u, 0u};
  }
  *(uint4*)(e16 + base) = o;
}

// ---------------------------------------------------------------------------
// DAG stage 0b: w1 [512,256] -> Bt [512][256] bf16 (P | Q split).
// ---------------------------------------------------------------------------
__global__ __launch_bounds__(256) void prep_w1T_pq(
    const float* __restrict__ w1, unsigned short* __restrict__ Bt) {
  int gid = blockIdx.x * 256 + threadIdx.x;  // 131072
  int n = gid >> 8, k = gid & 255;
  float v = (n < 256) ? w1[k * 256 + n] : w1[(256 + k) * 256 + (n - 256)];
  Bt[gid] = f2bf(v);
}

// ---------------------------------------------------------------------------
// DAG stage 2: s[r] = relu(P[leaf[r]] + Q[anc[r]] + b1) . w2
// ---------------------------------------------------------------------------
__global__ __launch_bounds__(256) void dag_score(
    const int* __restrict__ leaves, const int* __restrict__ anc,
    const unsigned short* __restrict__ PQ, const float* __restrict__ b1,
    const float* __restrict__ w2, float* __restrict__ s) {
  const int tid = threadIdx.x;
  const int l16 = tid & 15;
  const int r = blockIdx.x * 16 + (tid >> 4);

  float b1c[16], w2c[16];
#pragma unroll
  for (int j = 0; j < 4; ++j) {
    *(float4*)&b1c[j * 4] = *(const float4*)(b1 + l16 * 16 + j * 4);
    *(float4*)&w2c[j * 4] = *(const float4*)(w2 + l16 * 16 + j * 4);
  }

  const int nl = leaves[r], na = anc[r];
  const unsigned short* pp = PQ + (size_t)nl * 512 + l16 * 16;
  const unsigned short* qp = PQ + (size_t)na * 512 + 256 + l16 * 16;

  float acc = 0.f;
#pragma unroll
  for (int half = 0; half < 2; ++half) {
    uint4 pv = *(const uint4*)(pp + half * 8);
    uint4 qv = *(const uint4*)(qp + half * 8);
    const unsigned short* pu = (const unsigned short*)&pv;
    const unsigned short* qu = (const unsigned short*)&qv;
#pragma unroll
    for (int j = 0; j < 8; ++j) {
      float h = bf2f(pu[j]) + bf2f(qu[j]) + b1c[half * 8 + j];
      acc += fmaxf(h, 0.f) * w2c[half * 8 + j];
    }
  }
  acc += __shfl_xor(acc, 1, 64);
  acc += __shfl_xor(acc, 2, 64);
  acc += __shfl_xor(acc, 4, 64);
  acc += __shfl_xor(acc, 8, 64);
  if (l16 == 0) s[r] = acc;
}

// ---------------------------------------------------------------------------
// DAG stage 3: softmax over A=8, masked ancestor sum (bf16 emb) -> dict.
// ---------------------------------------------------------------------------
__global__ __launch_bounds__(256) void dag_finalize(
    const float* __restrict__ s, const float* __restrict__ masks,
    const int* __restrict__ anc, const float* __restrict__ b2,
    const unsigned short* __restrict__ emb16, float* __restrict__ dict) {
  const int c = blockIdx.x;
  const int t = threadIdx.x;
  __shared__ float sv[8], mv[8];
  __shared__ int nv[8];
  if (t < 8) {
    int idx = c * 8 + t;
    float m = masks[idx];
    sv[t] = s[idx] + b2[0] + (1.f - m) * VERY_NEG;
    mv[t] = m;
    nv[t] = anc[idx];
  }
  __syncthreads();
  float mx = -INFINITY;
#pragma unroll
  for (int a = 0; a < 8; ++a) mx = fmaxf(mx, sv[a]);
  float e[8], sum = 0.f;
#pragma unroll
  for (int a = 0; a < 8; ++a) { e[a] = __expf(sv[a] - mx); sum += e[a]; }
  float inv = 1.f / sum;
  float o = 0.f;
#pragma unroll
  for (int a = 0; a < 8; ++a)
    o += e[a] * inv * mv[a] * bf2f(emb16[(size_t)nv[a] * 256 + t]);
  dict[(size_t)(c + 1) * 256 + t] = o;
  if (c == 0) dict[t] = 0.f;
}

// ---------------------------------------------------------------------------
// Row gather -> fp32 AND bf16 (dual write; table read once).
// ---------------------------------------------------------------------------
__global__ __launch_bounds__(256) void gather_both(
    const int* __restrict__ ids, const float4* __restrict__ table,
    float4* __restrict__ outf, unsigned short* __restrict__ outb) {
  int gid = blockIdx.x * 256 + threadIdx.x;
  int row = gid >> 6;
  int c4 = gid & 63;
  float4 v = table[(size_t)ids[row] * 64 + c4];
  outf[gid] = v;
  uint2 o;
  o.x = pack2(v.x, v.y);
  o.y = pack2(v.z, v.w);
  *(uint2*)(outb + (size_t)gid * 4) = o;
}

// ---------------------------------------------------------------------------
// MFMA flash attention, v3: sum-via-ones-MFMA softmax, split-ks P buffer,
// swizzled LDS, 4 blocks/CU. (See round-3 notes.)
// ---------------------------------------------------------------------------
static __device__ __forceinline__ int vt_addr(int d, int col) {
  return d * 272 + ((((col) * 2) ^ (((d >> 3) & 3) << 4)) >> 1);
}
static __device__ __forceinline__ int ps_addr(int row, int col) {
  return row * 40 + ((((col) * 2) ^ (((row >> 2) & 3) << 4)) >> 1);
}

__global__ __launch_bounds__(256, 4) void attn_mfma(
    const unsigned short* __restrict__ q, const unsigned short* __restrict__ k,
    const unsigned short* __restrict__ v, const float* __restrict__ cm,
    unsigned short* __restrict__ ctx) {
  __shared__ unsigned short Vt[32 * 272];   // [d][seq], swizzled
  __shared__ unsigned short Ps[4][64 * 40]; // wave-private 64x32 P slab
  __shared__ float madd[256];
  const int b = blockIdx.x >> 3, h = blockIdx.x & 7;
  const int tid = threadIdx.x;
  const int wave = tid >> 6, lane = tid & 63;
  const int quad = lane >> 4, l15 = lane & 15;
  const size_t tokbase = (size_t)b * 256;
  const int hoff = h * 32;

  // V load + transpose (direct global -> scatter into swizzled Vt)
#pragma unroll
  for (int it = 0; it < 4; ++it) {
    int idx = tid + it * 256;
    int row = idx >> 2, c = idx & 3;
    uint4 w = *(const uint4*)(v + (tokbase + row) * 256 + hoff + c * 8);
    const unsigned short* wsp = (const unsigned short*)&w;
#pragma unroll
    for (int j = 0; j < 8; ++j) Vt[vt_addr(c * 8 + j, row)] = wsp[j];
  }
  madd[tid] = (1.f - cm[b * 256 + tid]) * VERY_NEG;
  __syncthreads();

  short8 qf[4];
#pragma unroll
  for (int mt = 0; mt < 4; ++mt) {
    size_t qrow = tokbase + wave * 64 + mt * 16 + l15;
    qf[mt] = *(const short8*)(q + qrow * 256 + hoff + quad * 8);
  }
  float madd_r[16];
#pragma unroll
  for (int nt = 0; nt < 16; ++nt) madd_r[nt] = madd[nt * 16 + l15];

  // constant ones-column B-fragment: B[k][0]=1, else 0.
  short8 vone;
#pragma unroll
  for (int j = 0; j < 8; ++j)
    ((unsigned short*)&vone)[j] = (l15 == 0) ? 0x3F80 : 0;

  floatx4 oa[4][2], oa_l[4];
#pragma unroll
  for (int mt = 0; mt < 4; ++mt) {
    oa_l[mt] = (floatx4){0.f, 0.f, 0.f, 0.f};
#pragma unroll
    for (int nd = 0; nd < 2; ++nd) oa[mt][nd] = (floatx4){0.f, 0.f, 0.f, 0.f};
  }

  const float scale = 0.17677669529663687f;  // 1/sqrt(32)
  unsigned short* Pw = &Ps[wave][0];

  for (int t = 0; t < 4; ++t) {
    // K fragments straight from global (L2-hit after first wave).
    short8 kf[4];
#pragma unroll
    for (int nt = 0; nt < 4; ++nt)
      kf[nt] = *(const short8*)(k + (tokbase + t * 64 + nt * 16 + l15) * 256 +
                                hoff + quad * 8);
    floatx4 sa[4][4];
#pragma unroll
    for (int mt = 0; mt < 4; ++mt)
#pragma unroll
      for (int nt = 0; nt < 4; ++nt) sa[mt][nt] = (floatx4){0.f, 0.f, 0.f, 0.f};
#pragma unroll
    for (int mt = 0; mt < 4; ++mt)
#pragma unroll
      for (int nt = 0; nt < 4; ++nt)
        sa[mt][nt] = __builtin_amdgcn_mfma_f32_16x16x32_bf16(
            qf[mt], kf[nt], sa[mt][nt], 0, 0, 0);

#pragma unroll
    for (int ks = 0; ks < 2; ++ks) {
      // exp + pack + write the 32-k slab (elementwise only).
#pragma unroll
      for (int mt = 0; mt < 4; ++mt)
#pragma unroll
        for (int n2 = 0; n2 < 2; ++n2) {
          int nt = ks * 2 + n2;
#pragma unroll
          for (int i = 0; i < 4; ++i) {
            float p = __expf(sa[mt][nt][i] * scale + madd_r[t * 4 + nt]);
            Pw[ps_addr(mt * 16 + quad * 4 + i, n2 * 16 + l15)] = f2bf(p);
          }
        }
      __asm__ __volatile__("s_waitcnt lgkmcnt(0)" ::: "memory");
      short8 vf[2];
#pragma unroll
      for (int nd = 0; nd < 2; ++nd)
        vf[nd] = *(const short8*)&Vt[vt_addr(nd * 16 + l15,
                                             t * 64 + ks * 32 + quad * 8)];
#pragma unroll
      for (int mt = 0; mt < 4; ++mt) {
        short8 pf = *(const short8*)&Pw[ps_addr(mt * 16 + l15, quad * 8)];
#pragma unroll
        for (int nd = 0; nd < 2; ++nd)
          oa[mt][nd] = __builtin_amdgcn_mfma_f32_16x16x32_bf16(
              pf, vf[nd], oa[mt][nd], 0, 0, 0);
        oa_l[mt] = __builtin_amdgcn_mfma_f32_16x16x32_bf16(
            pf, vone, oa_l[mt], 0, 0, 0);
      }
    }
  }

  // epilogue: broadcast row sums (held at l15==0 lanes), normalize, store.
  float inv[4][4];
#pragma unroll
  for (int mt = 0; mt < 4; ++mt)
#pragma unroll
    for (int i = 0; i < 4; ++i) {
      float l = __shfl(oa_l[mt][i], lane & 48, 64);
      inv[mt][i] = 1.f / l;
    }
#pragma unroll
  for (int mt = 0; mt < 4; ++mt)
#pragma unroll
    for (int nd = 0; nd < 2; ++nd)
#pragma unroll
      for (int i = 0; i < 4; ++i)
        Pw[ps_addr(mt * 16 + quad * 4 + i, nd * 16 + l15)] =
            f2bf(oa[mt][nd][i] * inv[mt][i]);
  __asm__ __volatile__("s_waitcnt lgkmcnt(0)" ::: "memory");
#pragma unroll
  for (int it = 0; it < 4; ++it) {
    int idx = it * 64 + lane;
    int row = idx >> 2, c = idx & 3;
    uint4 w = *(const uint4*)&Pw[ps_addr(row, c * 8)];
    *(uint4*)(ctx + (tokbase + wave * 64 + row) * 256 + hoff + c * 8) = w;
  }
}

// ---------------------------------------------------------------------------
// Attention pooling. 128 blocks x 512 thr: scores by first 4 waves, weighted
// sum split across si-halves (full SIMD coverage, serial loop halved).
// ---------------------------------------------------------------------------
__global__ __launch_bounds__(512) void pool_kernel(
    const float* __restrict__ x, const float* __restrict__ code_mask,
    const float* __restrict__ pw, const float* __restrict__ pb,
    float* __restrict__ out) {
  const int b = blockIdx.x;
  const int t = threadIdx.x;        // 0..511
  const int col = t & 255, half = t >> 8;
  __shared__ float ss[256];
  __shared__ float red[256];
  __shared__ float als[256];
  __shared__ float osum[512];
  const float* xb = x + (size_t)b * 256 * 256;

  if (t < 256) {
    float s = pb[0];
    for (int j = 0; j < 256; j += 4) {
      float4 xv = *(const float4*)(xb + (size_t)t * 256 + j);
      float4 wv = *(const float4*)(pw + j);
      s += xv.x * wv.x + xv.y * wv.y + xv.z * wv.z + xv.w * wv.w;
    }
    s += (1.f - code_mask[b * 256 + t]) * VERY_NEG;
    ss[t] = s; red[t] = s;
  }
  __syncthreads();
  for (int off = 128; off > 0; off >>= 1) {
    if (t < off) red[t] = fmaxf(red[t], red[t + off]);
    __syncthreads();
  }
  float m = red[0];
  __syncthreads();
  if (t < 256) {
    float e = __expf(ss[t] - m);
    als[t] = e; red[t] = e;
  }
  __syncthreads();
  for (int off = 128; off > 0; off >>= 1) {
    if (t < off) red[t] += red[t + off];
    __syncthreads();
  }
  float inv = 1.f / red[0];
  float o = 0.f;
  for (int si = half * 128; si < half * 128 + 128; ++si)
    o += als[si] * xb[(size_t)si * 256 + col];
  osum[t] = o;
  __syncthreads();
  if (t < 256) out[b * 256 + t] = (osum[t] + osum[t + 256]) * inv;
}

// ---------------------------------------------------------------------------
extern "C" void kernel_launch(void* const* d_in, const int* in_sizes, int n_in,
                              void* d_out, int out_size, void* d_ws,
                              size_t ws_size, hipStream_t stream) {
  const int* input_ids = (const int*)d_in[0];
  const float* code_mask = (const float*)d_in[1];
  const int* dx_leaves = (const int*)d_in[2];
  const int* dx_anc = (const int*)d_in[3];
  const float* dx_masks = (const float*)d_in[4];
  const float* embed_init_w = (const float*)d_in[5];
  const float* embed_inputs_w = (const float*)d_in[6];
  const float* attn_w1 = (const float*)d_in[7];
  const float* attn_b1 = (const float*)d_in[8];
  const float* attn_w2 = (const float*)d_in[9];
  const float* attn_b2 = (const float*)d_in[10];
  const float* pool_w = (const float*)d_in[11];
  const float* pool_b = (const float*)d_in[12];

  float* out = (float*)d_out;
  float* ws = (float*)d_ws;

  // workspace layout (floats)
  float* dict = ws;                      // 5,120,256
  float* xbuf = dict + 5120256;          // 8,388,608
  float* qb   = xbuf + 8388608;          // 8,388,608
  float* kb   = qb + 8388608;            // 8,388,608
  float* vb   = kb + 8388608;            // 8,388,608
  float* ctxb = vb + 8388608;            // 8,388,608
  float* wend = ctxb + 8388608;          // weight area (393,216 floats)

  // DAG-phase aliases over regions dead until the encoder phase:
  unsigned short* emb16  = (unsigned short*)xbuf;             // 6,422,528 ush
  unsigned short* pq16   = (unsigned short*)(xbuf + 3211264); // 12,845,056 ush (spills into qb)
  unsigned short* w1T_pq = (unsigned short*)kb;               // 131,072 ush
  float* sbuf = vb;                                           // 160,000 floats

  // encoder-phase aliases:
  unsigned short* xb16  = (unsigned short*)ctxb;  // bf16(x) pre-QKV, later ctx
  unsigned short* qkv16 = (unsigned short*)qb;    // q/k/v bf16, 16777216 stride
  unsigned short* xq16  = (unsigned short*)qb;    // bf16(x) post-WO (q dead)
  // bf16 weights:
  unsigned short* qkvT = (unsigned short*)wend;   // 196,608
  unsigned short* woT  = qkvT + 196608;           // 65,536
  unsigned short* fw1T = woT + 65536;             // 262,144
  unsigned short* fw2T = fw1T + 262144;           // 262,144

  // 1) DAG embedding -> dict_matrix (factored PQ path).
  cvt_emb16<<<3136, 256, 0, stream>>>(embed_init_w, emb16);
  prep_w1T_pq<<<512, 256, 0, stream>>>(attn_w1, w1T_pq);
  gemm_mfma<256, false, false, false, 1><<<dim3(4, 196), 256, 0, stream>>>(
      emb16, w1T_pq, nullptr, nullptr, nullptr, pq16, 512);
  dag_score<<<Rc / 16, 256, 0, stream>>>(dx_leaves, dx_anc, pq16, attn_b1,
                                         attn_w2, sbuf);
  dag_finalize<<<Cc, 256, 0, stream>>>(sbuf, dx_masks, dx_anc, attn_b2,
                                       emb16, dict);

  auto run_encoder = [&](const float* wq, const float* wk, const float* wv,
                         const float* wo, const float* fw1, const float* fb1,
                         const float* fw2, const float* fb2, float* final_out) {
    prep_weights<<<3072, 256, 0, stream>>>(wq, wk, wv, wo, fw1, fw2, qkvT,
                                           woT, fw1T, fw2T);
    // fused QKV: N=768, bf16 split-output into q/k/v buffers
    gemm_mfma<256, false, false, false, 3><<<dim3(6, 256), 256, 0, stream>>>(
        xb16, qkvT, nullptr, nullptr, nullptr, qkv16, 256);
    // MFMA flash attention -> bf16 ctx (into xb16 region; dead post-QKV)
    attn_mfma<<<Bc * NHc, 256, 0, stream>>>(qkv16, qkv16 + 16777216,
                                            qkv16 + 33554432, code_mask, xb16);
    // x += ctx @ wo  (fp32 resid out to xbuf, bf16 copy to xq16)
    gemm_mfma<256, false, false, true, 2><<<dim3(2, 256), 256, 0, stream>>>(
        xb16, woT, nullptr, xbuf, xbuf, xq16, 256);
    // fused FFN: hidden stays in LDS, no HBM round-trip
    ffn_fused<<<256, 256, 0, stream>>>(xq16, fw1T, fw2T, fb1, fb2, xbuf,
                                       final_out);
  };

  // 2) visit stream
  gather_both<<<8192, 256, 0, stream>>>(input_ids,
                                        (const float4*)embed_inputs_w,
                                        (float4*)xbuf, xb16);
  run_encoder((const float*)d_in[13], (const float*)d_in[14],
              (const float*)d_in[15], (const float*)d_in[16],
              (const float*)d_in[17], (const float*)d_in[18],
              (const float*)d_in[19], (const float*)d_in[20], out);

  // 3) dag stream
  gather_both<<<8192, 256, 0, stream>>>(input_ids, (const float4*)dict,
                                        (float4*)xbuf, xb16);
  run_encoder((const float*)d_in[21], (const float*)d_in[22],
              (const float*)d_in[23], (const float*)d_in[24],
              (const float*)d_in[25], (const float*)d_in[26],
              (const float*)d_in[27], (const float*)d_in[28], xbuf);

  pool_kernel<<<Bc, 512, 0, stream>>>(xbuf, code_mask, pool_w, pool_b,
                                      out + 8388608);
}

// Round 6
// 563.239 us; speedup vs baseline: 1.0073x; 1.0073x over previous
//
#include <hip/hip_runtime.h>
#include <hip/hip_bf16.h>
#include <math.h>

#define VERY_NEG (-1e30f)

// B=128, S=256, H=256, C=20000, NODES=25000, A=8, NH=8, d=32, FF=1024
constexpr int Bc = 128, Sc = 256, Hc = 256, Cc = 20000, Ac = 8, NHc = 8, DHc = 32, FFc = 1024;
constexpr int Mc = Bc * Sc;  // 32768 rows
constexpr int Rc = Cc * Ac;  // 160000 dag rows

typedef __attribute__((ext_vector_type(8))) short short8;
typedef __attribute__((ext_vector_type(4))) float floatx4;

static __device__ __forceinline__ unsigned short f2bf(float f) {
  union { float f; unsigned u; } v; v.f = f;
  unsigned r = v.u + 0x7FFF + ((v.u >> 16) & 1);   // RNE
  return (unsigned short)(r >> 16);
}
static __device__ __forceinline__ unsigned pack2(float lo, float hi) {
  return (unsigned)f2bf(lo) | ((unsigned)f2bf(hi) << 16);
}
static __device__ __forceinline__ float bf2f(unsigned short u) {
  union { unsigned u; float f; } v; v.u = ((unsigned)u) << 16; return v.f;
}

// async global->LDS, 16B per lane; lane i lands at base + i*16.
static __device__ __forceinline__ void glds16(const unsigned short* g,
                                              unsigned short* l) {
  __builtin_amdgcn_global_load_lds(
      (const __attribute__((address_space(1))) void*)g,
      (__attribute__((address_space(3))) void*)l, 16, 0, 0);
}

// ---------------------------------------------------------------------------
// Per-layer weight prep, one launch: wq/wk/wv -> qkvT[768][256],
// wo -> woT[256][256], fw1 -> fw1T[1024][256], fw2 -> fw2T[256][1024].
// ---------------------------------------------------------------------------
__global__ __launch_bounds__(256) void prep_weights(
    const float* __restrict__ wq, const float* __restrict__ wk,
    const float* __restrict__ wv, const float* __restrict__ wo,
    const float* __restrict__ fw1, const float* __restrict__ fw2,
    unsigned short* __restrict__ qkvT, unsigned short* __restrict__ woT,
    unsigned short* __restrict__ fw1T, unsigned short* __restrict__ fw2T) {
  int gid = blockIdx.x * 256 + threadIdx.x;
  if (gid < 196608) {
    int which = gid >> 16, rem = gid & 65535;
    int n = rem >> 8, k = rem & 255;
    const float* w = which == 0 ? wq : (which == 1 ? wk : wv);
    qkvT[gid] = f2bf(w[k * 256 + n]);
  } else if (gid < 262144) {
    int rem = gid - 196608;
    int n = rem >> 8, k = rem & 255;
    woT[rem] = f2bf(wo[k * 256 + n]);
  } else if (gid < 524288) {
    int rem = gid - 262144;
    int n = rem >> 8, k = rem & 255;   // n 0..1023
    fw1T[rem] = f2bf(fw1[k * 1024 + n]);
  } else {
    int rem = gid - 524288;
    int n = rem >> 10, k = rem & 1023; // n 0..255
    fw2T[rem] = f2bf(fw2[k * 256 + n]);
  }
}

// ---------------------------------------------------------------------------
// bf16 MFMA GEMM, glds staging, BK=64, XOR-swizzled unpadded LDS [128][64].
// XCD-aware bijective blockIdx swizzle (all launches have nwg%8==0).
// OUT: 0 fp32->Cf; 1 bf16->C2; 2 both; 3 bf16 QKV split (col>>8 buffer).
// ---------------------------------------------------------------------------
template <int K, bool BIAS, bool RELU, bool RESID, int OUT>
__global__ __launch_bounds__(256) void gemm_mfma(
    const unsigned short* __restrict__ A, const unsigned short* __restrict__ Bt,
    const float* __restrict__ bias, const float* __restrict__ resid,
    float* __restrict__ Cf, unsigned short* __restrict__ C2, int N) {
  __shared__ unsigned short As[128 * 64];
  __shared__ unsigned short Bs[128 * 64];
  const int tid = threadIdx.x;
  const int nwg = gridDim.x * gridDim.y;
  const int bid0 = blockIdx.y * gridDim.x + blockIdx.x;
  const int swz = (bid0 & 7) * (nwg >> 3) + (bid0 >> 3);
  const int rowBase = (swz / gridDim.x) * 128;
  const int colBase = (swz % gridDim.x) * 128;
  const int wave = tid >> 6, lane = tid & 63;
  const int wm = wave >> 1, wn = wave & 1;
  const int quad = lane >> 4, l15 = lane & 15;
  const int s8 = (((lane & 7) ^ (lane >> 3)) << 3);  // swizzled global chunk
  const int rs0 = (wave << 5) + (lane >> 3);         // staged row base
  const int swzf = l15 & 7;

  floatx4 acc[4][4];
#pragma unroll
  for (int mt = 0; mt < 4; ++mt)
#pragma unroll
    for (int nt = 0; nt < 4; ++nt) acc[mt][nt] = (floatx4){0.f, 0.f, 0.f, 0.f};

  for (int k0 = 0; k0 < K; k0 += 64) {
#pragma unroll
    for (int i = 0; i < 4; ++i) {
      int r = rs0 + (i << 3);
      int lb = wave * 2048 + i * 512;
      glds16(A + (size_t)(rowBase + r) * K + k0 + s8, &As[lb]);
      glds16(Bt + (size_t)(colBase + r) * K + k0 + s8, &Bs[lb]);
    }
    __syncthreads();
#pragma unroll
    for (int kk = 0; kk < 2; ++kk) {
      short8 af[4], bfr[4];
#pragma unroll
      for (int mt = 0; mt < 4; ++mt)
        af[mt] = *(const short8*)&As[(wm * 64 + mt * 16 + l15) * 64 +
                                     ((((kk << 2) | quad) ^ swzf) << 3)];
#pragma unroll
      for (int nt = 0; nt < 4; ++nt)
        bfr[nt] = *(const short8*)&Bs[(wn * 64 + nt * 16 + l15) * 64 +
                                      ((((kk << 2) | quad) ^ swzf) << 3)];
#pragma unroll
      for (int mt = 0; mt < 4; ++mt)
#pragma unroll
        for (int nt = 0; nt < 4; ++nt)
          acc[mt][nt] = __builtin_amdgcn_mfma_f32_16x16x32_bf16(
              af[mt], bfr[nt], acc[mt][nt], 0, 0, 0);
    }
    __syncthreads();
  }

#pragma unroll
  for (int mt = 0; mt < 4; ++mt) {
#pragma unroll
    for (int nt = 0; nt < 4; ++nt) {
      int col = colBase + wn * 64 + nt * 16 + l15;
      float bz = BIAS ? bias[col] : 0.f;
#pragma unroll
      for (int i = 0; i < 4; ++i) {
        int row = rowBase + wm * 64 + mt * 16 + quad * 4 + i;
        float v = acc[mt][nt][i];
        if (BIAS) v += bz;
        if (RELU) v = fmaxf(v, 0.f);
        if (RESID) v += resid[(size_t)row * N + col];
        if (OUT == 0) {
          Cf[(size_t)row * N + col] = v;
        } else if (OUT == 1) {
          C2[(size_t)row * N + col] = f2bf(v);
        } else if (OUT == 2) {
          Cf[(size_t)row * N + col] = v;
          C2[(size_t)row * N + col] = f2bf(v);
        } else {  // QKV split
          C2[(size_t)(col >> 8) * 16777216 + (size_t)row * 256 + (col & 255)] =
              f2bf(v);
        }
      }
    }
  }
}

// ---------------------------------------------------------------------------
// Fused FFN v2: out = relu(x@W1+b1)@W2 + b2 + resid, hidden stays in LDS.
// v1 failed at 1 block/CU (128KB LDS, VGPR 248): 1 wave/SIMD = zero latency
// hiding across the ~64 barriers/block. v2: 64-row panels, grid 512
// (= exactly 2 blocks/CU), LDS 80KB (Xs 32K + Ws 32K + Hs 16K), acc2[2][8]
// -> ~160 VGPR, 2 waves/SIMD: cross-block overlap covers barrier stalls.
// ---------------------------------------------------------------------------
__global__ __launch_bounds__(256, 2) void ffn_fused(
    const unsigned short* __restrict__ A, const unsigned short* __restrict__ w1T,
    const unsigned short* __restrict__ w2T, const float* __restrict__ b1,
    const float* __restrict__ b2, const float* __restrict__ resid,
    float* __restrict__ outC) {
  __shared__ unsigned short Xs[4][4096];  // x tile [64][256], 4 chunks [64][64]
  __shared__ unsigned short Ws[16384];    // W1 2x[128][64] / W2 [256][64]
  __shared__ unsigned short Hs[2][4096];  // h tile [64][128], 2 chunks [64][64]
  const int tid = threadIdx.x;
  const int wave = tid >> 6, lane = tid & 63;
  const int wm = wave >> 1, wn = wave & 1;
  const int quad = lane >> 4, l15 = lane & 15;
  const int s8 = (((lane & 7) ^ (lane >> 3)) << 3);
  const int rs0x = (wave << 4) + (lane >> 3);  // [64][64] staging rows
  const int rs0 = (wave << 5) + (lane >> 3);   // [128][64] staging rows
  const int rs0b = (wave << 6) + (lane >> 3);  // [256][64] staging rows
  const int swzf = l15 & 7;
  const int rowBase = blockIdx.x * 64;

  // stage x tile [64][256] once (completion via first __syncthreads)
#pragma unroll
  for (int kc = 0; kc < 4; ++kc)
#pragma unroll
    for (int i = 0; i < 2; ++i) {
      int r = rs0x + (i << 3);
      glds16(A + (size_t)(rowBase + r) * 256 + kc * 64 + s8,
             &Xs[kc][wave * 1024 + i * 512]);
    }

  floatx4 acc2[2][8];
#pragma unroll
  for (int mt = 0; mt < 2; ++mt)
#pragma unroll
    for (int nt = 0; nt < 8; ++nt) acc2[mt][nt] = (floatx4){0.f, 0.f, 0.f, 0.f};

  for (int nb = 0; nb < 8; ++nb) {
    floatx4 hacc[2][4];
#pragma unroll
    for (int mt = 0; mt < 2; ++mt)
#pragma unroll
      for (int nt = 0; nt < 4; ++nt) hacc[mt][nt] = (floatx4){0.f, 0.f, 0.f, 0.f};

    // ---- stage 1: h = x @ W1[:, nb*128:+128], K=256 in 2 halves ----
#pragma unroll
    for (int hf = 0; hf < 2; ++hf) {
#pragma unroll
      for (int kc = 0; kc < 2; ++kc)
#pragma unroll
        for (int i = 0; i < 4; ++i) {
          int r = rs0 + (i << 3);
          glds16(w1T + (size_t)(nb * 128 + r) * 256 + (hf * 2 + kc) * 64 + s8,
                 &Ws[kc * 8192 + wave * 2048 + i * 512]);
        }
      __syncthreads();
#pragma unroll
      for (int kc = 0; kc < 2; ++kc) {
        int kg = hf * 2 + kc;
#pragma unroll
        for (int kk = 0; kk < 2; ++kk) {
          short8 af[2], bfr[4];
#pragma unroll
          for (int mt = 0; mt < 2; ++mt)
            af[mt] = *(const short8*)&Xs[kg][(wm * 32 + mt * 16 + l15) * 64 +
                                            ((((kk << 2) | quad) ^ swzf) << 3)];
#pragma unroll
          for (int nt = 0; nt < 4; ++nt)
            bfr[nt] = *(const short8*)&Ws[kc * 8192 +
                                          (wn * 64 + nt * 16 + l15) * 64 +
                                          ((((kk << 2) | quad) ^ swzf) << 3)];
#pragma unroll
          for (int mt = 0; mt < 2; ++mt)
#pragma unroll
            for (int nt = 0; nt < 4; ++nt)
              hacc[mt][nt] = __builtin_amdgcn_mfma_f32_16x16x32_bf16(
                  af[mt], bfr[nt], hacc[mt][nt], 0, 0, 0);
        }
      }
      __syncthreads();  // all waves done reading Ws -> safe to restage
    }

    // ---- relu+b1, pack h into swizzled Hs; stage W2 kc2=0 concurrently ----
    float b1v[4];
#pragma unroll
    for (int nt = 0; nt < 4; ++nt)
      b1v[nt] = b1[nb * 128 + wn * 64 + nt * 16 + l15];
#pragma unroll
    for (int mt = 0; mt < 2; ++mt)
#pragma unroll
      for (int nt = 0; nt < 4; ++nt) {
        int nh = wn * 64 + nt * 16 + l15;
        int kc2 = nh >> 6, c6 = nh & 63;
#pragma unroll
        for (int i = 0; i < 4; ++i) {
          int row = wm * 32 + mt * 16 + quad * 4 + i;
          float hv = fmaxf(hacc[mt][nt][i] + b1v[nt], 0.f);
          Hs[kc2][row * 64 + ((((c6 >> 3) ^ (row & 7)) << 3) | (c6 & 7))] =
              f2bf(hv);
        }
      }
#pragma unroll
    for (int i = 0; i < 8; ++i) {  // W2 [256 out][64 k], kc2=0
      int r = rs0b + (i << 3);
      glds16(w2T + (size_t)r * 1024 + nb * 128 + s8,
             &Ws[wave * 4096 + i * 512]);
    }
    __syncthreads();

    // ---- stage 2: y += h @ W2[nb*128:+128, :], 2 k-chunks ----
#pragma unroll
    for (int kc2 = 0; kc2 < 2; ++kc2) {
      if (kc2 == 1) {
        __syncthreads();  // done reading Ws(kc2=0)
#pragma unroll
        for (int i = 0; i < 8; ++i) {
          int r = rs0b + (i << 3);
          glds16(w2T + (size_t)r * 1024 + nb * 128 + 64 + s8,
                 &Ws[wave * 4096 + i * 512]);
        }
        __syncthreads();
      }
#pragma unroll
      for (int kk = 0; kk < 2; ++kk) {
        short8 pf[2], bfr2[8];
#pragma unroll
        for (int mt = 0; mt < 2; ++mt)
          pf[mt] = *(const short8*)&Hs[kc2][(wm * 32 + mt * 16 + l15) * 64 +
                                            ((((kk << 2) | quad) ^ swzf) << 3)];
#pragma unroll
        for (int nt = 0; nt < 8; ++nt)
          bfr2[nt] = *(const short8*)&Ws[(wn * 128 + nt * 16 + l15) * 64 +
                                         ((((kk << 2) | quad) ^ swzf) << 3)];
#pragma unroll
        for (int mt = 0; mt < 2; ++mt)
#pragma unroll
          for (int nt = 0; nt < 8; ++nt)
            acc2[mt][nt] = __builtin_amdgcn_mfma_f32_16x16x32_bf16(
                pf[mt], bfr2[nt], acc2[mt][nt], 0, 0, 0);
      }
    }
    __syncthreads();  // done reading Ws & Hs before next nb overwrites
  }

  // ---- epilogue: + b2 + resid -> fp32 out ----
#pragma unroll
  for (int mt = 0; mt < 2; ++mt)
#pragma unroll
    for (int nt = 0; nt < 8; ++nt) {
      int col = wn * 128 + nt * 16 + l15;
      float bz = b2[col];
#pragma unroll
      for (int i = 0; i < 4; ++i) {
        int row = rowBase + wm * 32 + mt * 16 + quad * 4 + i;
        outC[(size_t)row * 256 + col] =
            acc2[mt][nt][i] + bz + resid[(size_t)row * 256 + col];
      }
    }
}

// ---------------------------------------------------------------------------
// DAG stage 0a: embed_init_w [25001][256] fp32 -> emb16 [25088][256] bf16
// ---------------------------------------------------------------------------
__global__ __launch_bounds__(256) void cvt_emb16(
    const float* __restrict__ emb, unsigned short* __restrict__ e16) {
  int gid = blockIdx.x * 256 + threadIdx.x;  // 802816 threads, 8 elems each
  int base = gid * 8;
  int row = base >> 8;
  uint4 o;
  if (row < 25001) {
    float4 a = *(const float4*)(emb + base);
    float4 b = *(const float4*)(emb + base + 4);
    o.x = pack2(a.x, a.y); o.y = pack2(a.z, a.w);
    o.z = pack2(b.x, b.y); o.w = pack2(b.z, b.w);
  } else {
    o = (uint4){0u, 0u, 0u, 0u};
  }
  *(uint4*)(e16 + base) = o;
}

// ---------------------------------------------------------------------------
// DAG stage 0b: w1 [512,256] -> Bt [512][256] bf16 (P | Q split).
// ---------------------------------------------------------------------------
__global__ __launch_bounds__(256) void prep_w1T_pq(
    const float* __restrict__ w1, unsigned short* __restrict__ Bt) {
  int gid = blockIdx.x * 256 + threadIdx.x;  // 131072
  int n = gid >> 8, k = gid & 255;
  float v = (n < 256) ? w1[k * 256 + n] : w1[(256 + k) * 256 + (n - 256)];
  Bt[gid] = f2bf(v);
}

// ---------------------------------------------------------------------------
// DAG stage 2: s[r] = relu(P[leaf[r]] + Q[anc[r]] + b1) . w2
// ---------------------------------------------------------------------------
__global__ __launch_bounds__(256) void dag_score(
    const int* __restrict__ leaves, const int* __restrict__ anc,
    const unsigned short* __restrict__ PQ, const float* __restrict__ b1,
    const float* __restrict__ w2, float* __restrict__ s) {
  const int tid = threadIdx.x;
  const int l16 = tid & 15;
  const int r = blockIdx.x * 16 + (tid >> 4);

  float b1c[16], w2c[16];
#pragma unroll
  for (int j = 0; j < 4; ++j) {
    *(float4*)&b1c[j * 4] = *(const float4*)(b1 + l16 * 16 + j * 4);
    *(float4*)&w2c[j * 4] = *(const float4*)(w2 + l16 * 16 + j * 4);
  }

  const int nl = leaves[r], na = anc[r];
  const unsigned short* pp = PQ + (size_t)nl * 512 + l16 * 16;
  const unsigned short* qp = PQ + (size_t)na * 512 + 256 + l16 * 16;

  float acc = 0.f;
#pragma unroll
  for (int half = 0; half < 2; ++half) {
    uint4 pv = *(const uint4*)(pp + half * 8);
    uint4 qv = *(const uint4*)(qp + half * 8);
    const unsigned short* pu = (const unsigned short*)&pv;
    const unsigned short* qu = (const unsigned short*)&qv;
#pragma unroll
    for (int j = 0; j < 8; ++j) {
      float h = bf2f(pu[j]) + bf2f(qu[j]) + b1c[half * 8 + j];
      acc += fmaxf(h, 0.f) * w2c[half * 8 + j];
    }
  }
  acc += __shfl_xor(acc, 1, 64);
  acc += __shfl_xor(acc, 2, 64);
  acc += __shfl_xor(acc, 4, 64);
  acc += __shfl_xor(acc, 8, 64);
  if (l16 == 0) s[r] = acc;
}

// ---------------------------------------------------------------------------
// DAG stage 3: softmax over A=8, masked ancestor sum (bf16 emb) -> dict.
// ---------------------------------------------------------------------------
__global__ __launch_bounds__(256) void dag_finalize(
    const float* __restrict__ s, const float* __restrict__ masks,
    const int* __restrict__ anc, const float* __restrict__ b2,
    const unsigned short* __restrict__ emb16, float* __restrict__ dict) {
  const int c = blockIdx.x;
  const int t = threadIdx.x;
  __shared__ float sv[8], mv[8];
  __shared__ int nv[8];
  if (t < 8) {
    int idx = c * 8 + t;
    float m = masks[idx];
    sv[t] = s[idx] + b2[0] + (1.f - m) * VERY_NEG;
    mv[t] = m;
    nv[t] = anc[idx];
  }
  __syncthreads();
  float mx = -INFINITY;
#pragma unroll
  for (int a = 0; a < 8; ++a) mx = fmaxf(mx, sv[a]);
  float e[8], sum = 0.f;
#pragma unroll
  for (int a = 0; a < 8; ++a) { e[a] = __expf(sv[a] - mx); sum += e[a]; }
  float inv = 1.f / sum;
  float o = 0.f;
#pragma unroll
  for (int a = 0; a < 8; ++a)
    o += e[a] * inv * mv[a] * bf2f(emb16[(size_t)nv[a] * 256 + t]);
  dict[(size_t)(c + 1) * 256 + t] = o;
  if (c == 0) dict[t] = 0.f;
}

// ---------------------------------------------------------------------------
// Row gather -> fp32 AND bf16 (dual write; table read once).
// ---------------------------------------------------------------------------
__global__ __launch_bounds__(256) void gather_both(
    const int* __restrict__ ids, const float4* __restrict__ table,
    float4* __restrict__ outf, unsigned short* __restrict__ outb) {
  int gid = blockIdx.x * 256 + threadIdx.x;
  int row = gid >> 6;
  int c4 = gid & 63;
  float4 v = table[(size_t)ids[row] * 64 + c4];
  outf[gid] = v;
  uint2 o;
  o.x = pack2(v.x, v.y);
  o.y = pack2(v.z, v.w);
  *(uint2*)(outb + (size_t)gid * 4) = o;
}

// ---------------------------------------------------------------------------
// MFMA flash attention, v3: sum-via-ones-MFMA softmax, split-ks P buffer,
// swizzled LDS, 4 blocks/CU. (See round-3 notes.)
// ---------------------------------------------------------------------------
static __device__ __forceinline__ int vt_addr(int d, int col) {
  return d * 272 + ((((col) * 2) ^ (((d >> 3) & 3) << 4)) >> 1);
}
static __device__ __forceinline__ int ps_addr(int row, int col) {
  return row * 40 + ((((col) * 2) ^ (((row >> 2) & 3) << 4)) >> 1);
}

__global__ __launch_bounds__(256, 4) void attn_mfma(
    const unsigned short* __restrict__ q, const unsigned short* __restrict__ k,
    const unsigned short* __restrict__ v, const float* __restrict__ cm,
    unsigned short* __restrict__ ctx) {
  __shared__ unsigned short Vt[32 * 272];   // [d][seq], swizzled
  __shared__ unsigned short Ps[4][64 * 40]; // wave-private 64x32 P slab
  __shared__ float madd[256];
  const int b = blockIdx.x >> 3, h = blockIdx.x & 7;
  const int tid = threadIdx.x;
  const int wave = tid >> 6, lane = tid & 63;
  const int quad = lane >> 4, l15 = lane & 15;
  const size_t tokbase = (size_t)b * 256;
  const int hoff = h * 32;

  // V load + transpose (direct global -> scatter into swizzled Vt)
#pragma unroll
  for (int it = 0; it < 4; ++it) {
    int idx = tid + it * 256;
    int row = idx >> 2, c = idx & 3;
    uint4 w = *(const uint4*)(v + (tokbase + row) * 256 + hoff + c * 8);
    const unsigned short* wsp = (const unsigned short*)&w;
#pragma unroll
    for (int j = 0; j < 8; ++j) Vt[vt_addr(c * 8 + j, row)] = wsp[j];
  }
  madd[tid] = (1.f - cm[b * 256 + tid]) * VERY_NEG;
  __syncthreads();

  short8 qf[4];
#pragma unroll
  for (int mt = 0; mt < 4; ++mt) {
    size_t qrow = tokbase + wave * 64 + mt * 16 + l15;
    qf[mt] = *(const short8*)(q + qrow * 256 + hoff + quad * 8);
  }
  float madd_r[16];
#pragma unroll
  for (int nt = 0; nt < 16; ++nt) madd_r[nt] = madd[nt * 16 + l15];

  // constant ones-column B-fragment: B[k][0]=1, else 0.
  short8 vone;
#pragma unroll
  for (int j = 0; j < 8; ++j)
    ((unsigned short*)&vone)[j] = (l15 == 0) ? 0x3F80 : 0;

  floatx4 oa[4][2], oa_l[4];
#pragma unroll
  for (int mt = 0; mt < 4; ++mt) {
    oa_l[mt] = (floatx4){0.f, 0.f, 0.f, 0.f};
#pragma unroll
    for (int nd = 0; nd < 2; ++nd) oa[mt][nd] = (floatx4){0.f, 0.f, 0.f, 0.f};
  }

  const float scale = 0.17677669529663687f;  // 1/sqrt(32)
  unsigned short* Pw = &Ps[wave][0];

  for (int t = 0; t < 4; ++t) {
    // K fragments straight from global (L2-hit after first wave).
    short8 kf[4];
#pragma unroll
    for (int nt = 0; nt < 4; ++nt)
      kf[nt] = *(const short8*)(k + (tokbase + t * 64 + nt * 16 + l15) * 256 +
                                hoff + quad * 8);
    floatx4 sa[4][4];
#pragma unroll
    for (int mt = 0; mt < 4; ++mt)
#pragma unroll
      for (int nt = 0; nt < 4; ++nt) sa[mt][nt] = (floatx4){0.f, 0.f, 0.f, 0.f};
#pragma unroll
    for (int mt = 0; mt < 4; ++mt)
#pragma unroll
      for (int nt = 0; nt < 4; ++nt)
        sa[mt][nt] = __builtin_amdgcn_mfma_f32_16x16x32_bf16(
            qf[mt], kf[nt], sa[mt][nt], 0, 0, 0);

#pragma unroll
    for (int ks = 0; ks < 2; ++ks) {
      // exp + pack + write the 32-k slab (elementwise only).
#pragma unroll
      for (int mt = 0; mt < 4; ++mt)
#pragma unroll
        for (int n2 = 0; n2 < 2; ++n2) {
          int nt = ks * 2 + n2;
#pragma unroll
          for (int i = 0; i < 4; ++i) {
            float p = __expf(sa[mt][nt][i] * scale + madd_r[t * 4 + nt]);
            Pw[ps_addr(mt * 16 + quad * 4 + i, n2 * 16 + l15)] = f2bf(p);
          }
        }
      __asm__ __volatile__("s_waitcnt lgkmcnt(0)" ::: "memory");
      short8 vf[2];
#pragma unroll
      for (int nd = 0; nd < 2; ++nd)
        vf[nd] = *(const short8*)&Vt[vt_addr(nd * 16 + l15,
                                             t * 64 + ks * 32 + quad * 8)];
#pragma unroll
      for (int mt = 0; mt < 4; ++mt) {
        short8 pf = *(const short8*)&Pw[ps_addr(mt * 16 + l15, quad * 8)];
#pragma unroll
        for (int nd = 0; nd < 2; ++nd)
          oa[mt][nd] = __builtin_amdgcn_mfma_f32_16x16x32_bf16(
              pf, vf[nd], oa[mt][nd], 0, 0, 0);
        oa_l[mt] = __builtin_amdgcn_mfma_f32_16x16x32_bf16(
            pf, vone, oa_l[mt], 0, 0, 0);
      }
    }
  }

  // epilogue: broadcast row sums (held at l15==0 lanes), normalize, store.
  float inv[4][4];
#pragma unroll
  for (int mt = 0; mt < 4; ++mt)
#pragma unroll
    for (int i = 0; i < 4; ++i) {
      float l = __shfl(oa_l[mt][i], lane & 48, 64);
      inv[mt][i] = 1.f / l;
    }
#pragma unroll
  for (int mt = 0; mt < 4; ++mt)
#pragma unroll
    for (int nd = 0; nd < 2; ++nd)
#pragma unroll
      for (int i = 0; i < 4; ++i)
        Pw[ps_addr(mt * 16 + quad * 4 + i, nd * 16 + l15)] =
            f2bf(oa[mt][nd][i] * inv[mt][i]);
  __asm__ __volatile__("s_waitcnt lgkmcnt(0)" ::: "memory");
#pragma unroll
  for (int it = 0; it < 4; ++it) {
    int idx = it * 64 + lane;
    int row = idx >> 2, c = idx & 3;
    uint4 w = *(const uint4*)&Pw[ps_addr(row, c * 8)];
    *(uint4*)(ctx + (tokbase + wave * 64 + row) * 256 + hoff + c * 8) = w;
  }
}

// ---------------------------------------------------------------------------
// Attention pooling. 128 blocks x 512 thr: scores by first 4 waves, weighted
// sum split across si-halves (full SIMD coverage, serial loop halved).
// ---------------------------------------------------------------------------
__global__ __launch_bounds__(512) void pool_kernel(
    const float* __restrict__ x, const float* __restrict__ code_mask,
    const float* __restrict__ pw, const float* __restrict__ pb,
    float* __restrict__ out) {
  const int b = blockIdx.x;
  const int t = threadIdx.x;        // 0..511
  const int col = t & 255, half = t >> 8;
  __shared__ float ss[256];
  __shared__ float red[256];
  __shared__ float als[256];
  __shared__ float osum[512];
  const float* xb = x + (size_t)b * 256 * 256;

  if (t < 256) {
    float s = pb[0];
    for (int j = 0; j < 256; j += 4) {
      float4 xv = *(const float4*)(xb + (size_t)t * 256 + j);
      float4 wv = *(const float4*)(pw + j);
      s += xv.x * wv.x + xv.y * wv.y + xv.z * wv.z + xv.w * wv.w;
    }
    s += (1.f - code_mask[b * 256 + t]) * VERY_NEG;
    ss[t] = s; red[t] = s;
  }
  __syncthreads();
  for (int off = 128; off > 0; off >>= 1) {
    if (t < off) red[t] = fmaxf(red[t], red[t + off]);
    __syncthreads();
  }
  float m = red[0];
  __syncthreads();
  if (t < 256) {
    float e = __expf(ss[t] - m);
    als[t] = e; red[t] = e;
  }
  __syncthreads();
  for (int off = 128; off > 0; off >>= 1) {
    if (t < off) red[t] += red[t + off];
    __syncthreads();
  }
  float inv = 1.f / red[0];
  float o = 0.f;
  for (int si = half * 128; si < half * 128 + 128; ++si)
    o += als[si] * xb[(size_t)si * 256 + col];
  osum[t] = o;
  __syncthreads();
  if (t < 256) out[b * 256 + t] = (osum[t] + osum[t + 256]) * inv;
}

// ---------------------------------------------------------------------------
extern "C" void kernel_launch(void* const* d_in, const int* in_sizes, int n_in,
                              void* d_out, int out_size, void* d_ws,
                              size_t ws_size, hipStream_t stream) {
  const int* input_ids = (const int*)d_in[0];
  const float* code_mask = (const float*)d_in[1];
  const int* dx_leaves = (const int*)d_in[2];
  const int* dx_anc = (const int*)d_in[3];
  const float* dx_masks = (const float*)d_in[4];
  const float* embed_init_w = (const float*)d_in[5];
  const float* embed_inputs_w = (const float*)d_in[6];
  const float* attn_w1 = (const float*)d_in[7];
  const float* attn_b1 = (const float*)d_in[8];
  const float* attn_w2 = (const float*)d_in[9];
  const float* attn_b2 = (const float*)d_in[10];
  const float* pool_w = (const float*)d_in[11];
  const float* pool_b = (const float*)d_in[12];

  float* out = (float*)d_out;
  float* ws = (float*)d_ws;

  // workspace layout (floats)
  float* dict = ws;                      // 5,120,256
  float* xbuf = dict + 5120256;          // 8,388,608
  float* qb   = xbuf + 8388608;          // 8,388,608
  float* kb   = qb + 8388608;            // 8,388,608
  float* vb   = kb + 8388608;            // 8,388,608
  float* ctxb = vb + 8388608;            // 8,388,608
  float* wend = ctxb + 8388608;          // weight area (393,216 floats)

  // DAG-phase aliases over regions dead until the encoder phase:
  unsigned short* emb16  = (unsigned short*)xbuf;             // 6,422,528 ush
  unsigned short* pq16   = (unsigned short*)(xbuf + 3211264); // 12,845,056 ush (spills into qb)
  unsigned short* w1T_pq = (unsigned short*)kb;               // 131,072 ush
  float* sbuf = vb;                                           // 160,000 floats

  // encoder-phase aliases:
  unsigned short* xb16  = (unsigned short*)ctxb;  // bf16(x) pre-QKV, later ctx
  unsigned short* qkv16 = (unsigned short*)qb;    // q/k/v bf16, 16777216 stride
  unsigned short* xq16  = (unsigned short*)qb;    // bf16(x) post-WO (q dead)
  // bf16 weights:
  unsigned short* qkvT = (unsigned short*)wend;   // 196,608
  unsigned short* woT  = qkvT + 196608;           // 65,536
  unsigned short* fw1T = woT + 65536;             // 262,144
  unsigned short* fw2T = fw1T + 262144;           // 262,144

  // 1) DAG embedding -> dict_matrix (factored PQ path).
  cvt_emb16<<<3136, 256, 0, stream>>>(embed_init_w, emb16);
  prep_w1T_pq<<<512, 256, 0, stream>>>(attn_w1, w1T_pq);
  gemm_mfma<256, false, false, false, 1><<<dim3(4, 196), 256, 0, stream>>>(
      emb16, w1T_pq, nullptr, nullptr, nullptr, pq16, 512);
  dag_score<<<Rc / 16, 256, 0, stream>>>(dx_leaves, dx_anc, pq16, attn_b1,
                                         attn_w2, sbuf);
  dag_finalize<<<Cc, 256, 0, stream>>>(sbuf, dx_masks, dx_anc, attn_b2,
                                       emb16, dict);

  auto run_encoder = [&](const float* wq, const float* wk, const float* wv,
                         const float* wo, const float* fw1, const float* fb1,
                         const float* fw2, const float* fb2, float* final_out) {
    prep_weights<<<3072, 256, 0, stream>>>(wq, wk, wv, wo, fw1, fw2, qkvT,
                                           woT, fw1T, fw2T);
    // fused QKV: N=768, bf16 split-output into q/k/v buffers
    gemm_mfma<256, false, false, false, 3><<<dim3(6, 256), 256, 0, stream>>>(
        xb16, qkvT, nullptr, nullptr, nullptr, qkv16, 256);
    // MFMA flash attention -> bf16 ctx (into xb16 region; dead post-QKV)
    attn_mfma<<<Bc * NHc, 256, 0, stream>>>(qkv16, qkv16 + 16777216,
                                            qkv16 + 33554432, code_mask, xb16);
    // x += ctx @ wo  (fp32 resid out to xbuf, bf16 copy to xq16)
    gemm_mfma<256, false, false, true, 2><<<dim3(2, 256), 256, 0, stream>>>(
        xb16, woT, nullptr, xbuf, xbuf, xq16, 256);
    // fused FFN v2: 64-row panels, 2 blocks/CU, hidden stays in LDS
    ffn_fused<<<512, 256, 0, stream>>>(xq16, fw1T, fw2T, fb1, fb2, xbuf,
                                       final_out);
  };

  // 2) visit stream
  gather_both<<<8192, 256, 0, stream>>>(input_ids,
                                        (const float4*)embed_inputs_w,
                                        (float4*)xbuf, xb16);
  run_encoder((const float*)d_in[13], (const float*)d_in[14],
              (const float*)d_in[15], (const float*)d_in[16],
              (const float*)d_in[17], (const float*)d_in[18],
              (const float*)d_in[19], (const float*)d_in[20], out);

  // 3) dag stream
  gather_both<<<8192, 256, 0, stream>>>(input_ids, (const float4*)dict,
                                        (float4*)xbuf, xb16);
  run_encoder((const float*)d_in[21], (const float*)d_in[22],
              (const float*)d_in[23], (const float*)d_in[24],
              (const float*)d_in[25], (const float*)d_in[26],
              (const float*)d_in[27], (const float*)d_in[28], xbuf);

  pool_kernel<<<Bc, 512, 0, stream>>>(xbuf, code_mask, pool_w, pool_b,
                                      out + 8388608);
}

// Round 7
// 556.186 us; speedup vs baseline: 1.0200x; 1.0127x over previous
//
#include <hip/hip_runtime.h>
#include <hip/hip_bf16.h>
#include <math.h>

#define VERY_NEG (-1e30f)

// B=128, S=256, H=256, C=20000, NODES=25000, A=8, NH=8, d=32, FF=1024
constexpr int Bc = 128, Sc = 256, Hc = 256, Cc = 20000, Ac = 8, NHc = 8, DHc = 32, FFc = 1024;
constexpr int Mc = Bc * Sc;  // 32768 rows
constexpr int Rc = Cc * Ac;  // 160000 dag rows

typedef __attribute__((ext_vector_type(8))) short short8;
typedef __attribute__((ext_vector_type(4))) float floatx4;

static __device__ __forceinline__ unsigned short f2bf(float f) {
  union { float f; unsigned u; } v; v.f = f;
  unsigned r = v.u + 0x7FFF + ((v.u >> 16) & 1);   // RNE
  return (unsigned short)(r >> 16);
}
static __device__ __forceinline__ unsigned pack2(float lo, float hi) {
  return (unsigned)f2bf(lo) | ((unsigned)f2bf(hi) << 16);
}
static __device__ __forceinline__ float bf2f(unsigned short u) {
  union { unsigned u; float f; } v; v.u = ((unsigned)u) << 16; return v.f;
}

// async global->LDS, 16B per lane; lane i lands at base + i*16.
static __device__ __forceinline__ void glds16(const unsigned short* g,
                                              unsigned short* l) {
  __builtin_amdgcn_global_load_lds(
      (const __attribute__((address_space(1))) void*)g,
      (__attribute__((address_space(3))) void*)l, 16, 0, 0);
}

// ---------------------------------------------------------------------------
// Per-layer weight prep v2: 64x64 LDS-tile transpose, coalesced both sides.
// (old version read fp32 at 1KB stride: ~16x fetch amplification.)
// Tile map: blk 0-47 wq/wk/wv -> qkvT, 48-63 wo -> woT,
//           64-127 fw1 [256][1024] -> fw1T, 128-191 fw2 [1024][256] -> fw2T.
// ---------------------------------------------------------------------------
__global__ __launch_bounds__(256) void prep_weights(
    const float* __restrict__ wq, const float* __restrict__ wk,
    const float* __restrict__ wv, const float* __restrict__ wo,
    const float* __restrict__ fw1, const float* __restrict__ fw2,
    unsigned short* __restrict__ qkvT, unsigned short* __restrict__ woT,
    unsigned short* __restrict__ fw1T, unsigned short* __restrict__ fw2T) {
  __shared__ float T[64][65];
  const int t = blockIdx.x;
  const float* src;
  unsigned short* dst;
  int R, Cn, tr, tc;
  if (t < 64) {  // 256x256 matrices, 16 tiles each
    int m = t >> 4, tt = t & 15;
    src = m == 0 ? wq : (m == 1 ? wk : (m == 2 ? wv : wo));
    dst = m < 3 ? qkvT + m * 65536 : woT;
    R = 256; Cn = 256; tr = tt >> 2; tc = tt & 3;
  } else if (t < 128) {  // fw1 [256][1024]
    int tt = t - 64;
    src = fw1; dst = fw1T; R = 256; Cn = 1024;
    tr = tt >> 4; tc = tt & 15;
  } else {               // fw2 [1024][256]
    int tt = t - 128;
    src = fw2; dst = fw2T; R = 1024; Cn = 256;
    tr = tt >> 2; tc = tt & 3;
  }
  const int r0 = threadIdx.x >> 4, c4 = threadIdx.x & 15;
#pragma unroll
  for (int it = 0; it < 4; ++it) {
    int row = it * 16 + r0;
    *(float4*)&T[row][c4 * 4] =
        *(const float4*)(src + (size_t)(tr * 64 + row) * Cn + tc * 64 + c4 * 4);
  }
  __syncthreads();
  const int c0 = threadIdx.x >> 2, seg = threadIdx.x & 3;
  unsigned short tmp[16];
#pragma unroll
  for (int j = 0; j < 16; ++j) tmp[j] = f2bf(T[seg * 16 + j][c0]);
  unsigned short* dp = dst + (size_t)(tc * 64 + c0) * R + tr * 64 + seg * 16;
  *(uint4*)dp = *(uint4*)&tmp[0];
  *(uint4*)(dp + 8) = *(uint4*)&tmp[8];
}

// ---------------------------------------------------------------------------
// bf16 MFMA GEMM, glds staging, BK=64, XOR-swizzled unpadded LDS [128][64].
// XCD-aware bijective blockIdx swizzle (all launches have nwg%8==0).
// OUT: 0 fp32->Cf; 1 bf16->C2; 2 both; 3 bf16 QKV split (col>>8 buffer).
// ---------------------------------------------------------------------------
template <int K, bool BIAS, bool RELU, bool RESID, int OUT>
__global__ __launch_bounds__(256) void gemm_mfma(
    const unsigned short* __restrict__ A, const unsigned short* __restrict__ Bt,
    const float* __restrict__ bias, const float* __restrict__ resid,
    float* __restrict__ Cf, unsigned short* __restrict__ C2, int N) {
  __shared__ unsigned short As[128 * 64];
  __shared__ unsigned short Bs[128 * 64];
  const int tid = threadIdx.x;
  const int nwg = gridDim.x * gridDim.y;
  const int bid0 = blockIdx.y * gridDim.x + blockIdx.x;
  const int swz = (bid0 & 7) * (nwg >> 3) + (bid0 >> 3);
  const int rowBase = (swz / gridDim.x) * 128;
  const int colBase = (swz % gridDim.x) * 128;
  const int wave = tid >> 6, lane = tid & 63;
  const int wm = wave >> 1, wn = wave & 1;
  const int quad = lane >> 4, l15 = lane & 15;
  const int s8 = (((lane & 7) ^ (lane >> 3)) << 3);  // swizzled global chunk
  const int rs0 = (wave << 5) + (lane >> 3);         // staged row base
  const int swzf = l15 & 7;

  floatx4 acc[4][4];
#pragma unroll
  for (int mt = 0; mt < 4; ++mt)
#pragma unroll
    for (int nt = 0; nt < 4; ++nt) acc[mt][nt] = (floatx4){0.f, 0.f, 0.f, 0.f};

  for (int k0 = 0; k0 < K; k0 += 64) {
#pragma unroll
    for (int i = 0; i < 4; ++i) {
      int r = rs0 + (i << 3);
      int lb = wave * 2048 + i * 512;
      glds16(A + (size_t)(rowBase + r) * K + k0 + s8, &As[lb]);
      glds16(Bt + (size_t)(colBase + r) * K + k0 + s8, &Bs[lb]);
    }
    __syncthreads();
#pragma unroll
    for (int kk = 0; kk < 2; ++kk) {
      short8 af[4], bfr[4];
#pragma unroll
      for (int mt = 0; mt < 4; ++mt)
        af[mt] = *(const short8*)&As[(wm * 64 + mt * 16 + l15) * 64 +
                                     ((((kk << 2) | quad) ^ swzf) << 3)];
#pragma unroll
      for (int nt = 0; nt < 4; ++nt)
        bfr[nt] = *(const short8*)&Bs[(wn * 64 + nt * 16 + l15) * 64 +
                                      ((((kk << 2) | quad) ^ swzf) << 3)];
#pragma unroll
      for (int mt = 0; mt < 4; ++mt)
#pragma unroll
        for (int nt = 0; nt < 4; ++nt)
          acc[mt][nt] = __builtin_amdgcn_mfma_f32_16x16x32_bf16(
              af[mt], bfr[nt], acc[mt][nt], 0, 0, 0);
    }
    __syncthreads();
  }

#pragma unroll
  for (int mt = 0; mt < 4; ++mt) {
#pragma unroll
    for (int nt = 0; nt < 4; ++nt) {
      int col = colBase + wn * 64 + nt * 16 + l15;
      float bz = BIAS ? bias[col] : 0.f;
#pragma unroll
      for (int i = 0; i < 4; ++i) {
        int row = rowBase + wm * 64 + mt * 16 + quad * 4 + i;
        float v = acc[mt][nt][i];
        if (BIAS) v += bz;
        if (RELU) v = fmaxf(v, 0.f);
        if (RESID) v += resid[(size_t)row * N + col];
        if (OUT == 0) {
          Cf[(size_t)row * N + col] = v;
        } else if (OUT == 1) {
          C2[(size_t)row * N + col] = f2bf(v);
        } else if (OUT == 2) {
          Cf[(size_t)row * N + col] = v;
          C2[(size_t)row * N + col] = f2bf(v);
        } else {  // QKV split
          C2[(size_t)(col >> 8) * 16777216 + (size_t)row * 256 + (col & 255)] =
              f2bf(v);
        }
      }
    }
  }
}

// ---------------------------------------------------------------------------
// Fused FFN v3: 512 threads (8 waves), 128 rows/block, grid 256 (1 block/CU,
// 2 waves/SIMD). x A-fragments live in REGISTERS (loaded once, no per-nb LDS
// re-reads); W1 [128][256] / W2 [256][128] slices stage into ONE reused 64KB
// buffer (W traffic per CU halved vs v2); Hs [128][128] 32KB. 4 barriers/nb.
// LDS 96KB. hidden never touches HBM.
// ---------------------------------------------------------------------------
__global__ __launch_bounds__(512, 2) void ffn_fused(
    const unsigned short* __restrict__ A, const unsigned short* __restrict__ w1T,
    const unsigned short* __restrict__ w2T, const float* __restrict__ b1,
    const float* __restrict__ b2, const float* __restrict__ resid,
    float* __restrict__ outC) {
  __shared__ unsigned short WsA[32768];  // 64KB: x stage, then W1/W2 slices
  __shared__ unsigned short Hs[16384];   // 32KB: h tile [128][128], 2 chunks
  const int tid = threadIdx.x;
  const int wave = tid >> 6, lane = tid & 63;
  const int wm = wave >> 1, wn = wave & 1;
  const int quad = lane >> 4, l15 = lane & 15;
  const int s8 = (((lane & 7) ^ (lane >> 3)) << 3);
  const int swz = l15 & 7;
  const int rowBase = blockIdx.x * 128;

  // ---- phase 0: stage x [128][256] (4 chunks [128][64]) then pull this
  //      wave's A-fragments into registers; WsA is then free for weights ----
#pragma unroll
  for (int kc = 0; kc < 4; ++kc)
#pragma unroll
    for (int i = 0; i < 2; ++i) {
      int rb = wave * 16 + i * 8;
      glds16(A + (size_t)(rowBase + rb + (lane >> 3)) * 256 + kc * 64 + s8,
             &WsA[kc * 8192 + rb * 64]);
    }
  __syncthreads();
  short8 af[2][8];
#pragma unroll
  for (int mt = 0; mt < 2; ++mt) {
    int row = wm * 32 + mt * 16 + l15;
#pragma unroll
    for (int gk = 0; gk < 8; ++gk)
      af[mt][gk] =
          *(const short8*)&WsA[(gk >> 1) * 8192 + row * 64 +
                               (((((gk & 1) << 2) | quad) ^ swz) << 3)];
  }
  __syncthreads();

  floatx4 acc2[2][8];
#pragma unroll
  for (int mt = 0; mt < 2; ++mt)
#pragma unroll
    for (int nt = 0; nt < 8; ++nt) acc2[mt][nt] = (floatx4){0.f, 0.f, 0.f, 0.f};

  for (int nb = 0; nb < 8; ++nb) {
    // ---- stage W1 slice [128 hidden][256 k] (4 chunks [128][64]) ----
#pragma unroll
    for (int kc = 0; kc < 4; ++kc)
#pragma unroll
      for (int i = 0; i < 2; ++i) {
        int rb = wave * 16 + i * 8;
        glds16(w1T + (size_t)(nb * 128 + rb + (lane >> 3)) * 256 + kc * 64 + s8,
               &WsA[kc * 8192 + rb * 64]);
      }
    __syncthreads();

    // ---- h = x @ W1 slice ----
    floatx4 hacc[2][4];
#pragma unroll
    for (int mt = 0; mt < 2; ++mt)
#pragma unroll
      for (int nt = 0; nt < 4; ++nt) hacc[mt][nt] = (floatx4){0.f, 0.f, 0.f, 0.f};
#pragma unroll
    for (int gk = 0; gk < 8; ++gk) {
      short8 bfr[4];
#pragma unroll
      for (int nt = 0; nt < 4; ++nt) {
        int rw = wn * 64 + nt * 16 + l15;
        bfr[nt] = *(const short8*)&WsA[(gk >> 1) * 8192 + rw * 64 +
                                       (((((gk & 1) << 2) | quad) ^ swz) << 3)];
      }
#pragma unroll
      for (int mt = 0; mt < 2; ++mt)
#pragma unroll
        for (int nt = 0; nt < 4; ++nt)
          hacc[mt][nt] = __builtin_amdgcn_mfma_f32_16x16x32_bf16(
              af[mt][gk], bfr[nt], hacc[mt][nt], 0, 0, 0);
    }

    // ---- relu+b1, pack h -> swizzled Hs ----
    float b1v[4];
#pragma unroll
    for (int nt = 0; nt < 4; ++nt)
      b1v[nt] = b1[nb * 128 + wn * 64 + nt * 16 + l15];
#pragma unroll
    for (int mt = 0; mt < 2; ++mt)
#pragma unroll
      for (int nt = 0; nt < 4; ++nt) {
        int c = wn * 64 + nt * 16 + l15;  // 0..127 within h tile
        int hc = c >> 6, c6 = c & 63;
#pragma unroll
        for (int i = 0; i < 4; ++i) {
          int row = wm * 32 + mt * 16 + quad * 4 + i;
          float hv = fmaxf(hacc[mt][nt][i] + b1v[nt], 0.f);
          Hs[hc * 8192 + row * 64 +
             ((((c6 >> 3) ^ (row & 7)) << 3) | (c6 & 7))] = f2bf(hv);
        }
      }
    __syncthreads();  // W1 reads + Hs writes done -> restage WsA

    // ---- stage W2 slice [256 out][128 k] (2 chunks [256][64]) ----
#pragma unroll
    for (int kc = 0; kc < 2; ++kc)
#pragma unroll
      for (int i = 0; i < 4; ++i) {
        int rb = wave * 32 + i * 8;
        glds16(w2T + (size_t)(rb + (lane >> 3)) * 1024 + nb * 128 + kc * 64 + s8,
               &WsA[kc * 16384 + rb * 64]);
      }
    __syncthreads();

    // ---- y += h @ W2 slice ----
#pragma unroll
    for (int gk = 0; gk < 4; ++gk) {
      short8 pf[2], bfr2[8];
#pragma unroll
      for (int mt = 0; mt < 2; ++mt) {
        int row = wm * 32 + mt * 16 + l15;
        pf[mt] = *(const short8*)&Hs[(gk >> 1) * 8192 + row * 64 +
                                     (((((gk & 1) << 2) | quad) ^ swz) << 3)];
      }
#pragma unroll
      for (int nt = 0; nt < 8; ++nt) {
        int rw = wn * 128 + nt * 16 + l15;
        bfr2[nt] = *(const short8*)&WsA[(gk >> 1) * 16384 + rw * 64 +
                                        (((((gk & 1) << 2) | quad) ^ swz) << 3)];
      }
#pragma unroll
      for (int mt = 0; mt < 2; ++mt)
#pragma unroll
        for (int nt = 0; nt < 8; ++nt)
          acc2[mt][nt] = __builtin_amdgcn_mfma_f32_16x16x32_bf16(
              pf[mt], bfr2[nt], acc2[mt][nt], 0, 0, 0);
    }
    __syncthreads();  // WsA & Hs reads done before next nb overwrites
  }

  // ---- epilogue: + b2 + resid -> fp32 out ----
#pragma unroll
  for (int mt = 0; mt < 2; ++mt)
#pragma unroll
    for (int nt = 0; nt < 8; ++nt) {
      int col = wn * 128 + nt * 16 + l15;
      float bz = b2[col];
#pragma unroll
      for (int i = 0; i < 4; ++i) {
        int row = rowBase + wm * 32 + mt * 16 + quad * 4 + i;
        outC[(size_t)row * 256 + col] =
            acc2[mt][nt][i] + bz + resid[(size_t)row * 256 + col];
      }
    }
}

// ---------------------------------------------------------------------------
// DAG stage 0a: embed_init_w [25001][256] fp32 -> emb16 [25088][256] bf16
// ---------------------------------------------------------------------------
__global__ __launch_bounds__(256) void cvt_emb16(
    const float* __restrict__ emb, unsigned short* __restrict__ e16) {
  int gid = blockIdx.x * 256 + threadIdx.x;  // 802816 threads, 8 elems each
  int base = gid * 8;
  int row = base >> 8;
  uint4 o;
  if (row < 25001) {
    float4 a = *(const float4*)(emb + base);
    float4 b = *(const float4*)(emb + base + 4);
    o.x = pack2(a.x, a.y); o.y = pack2(a.z, a.w);
    o.z = pack2(b.x, b.y); o.w = pack2(b.z, b.w);
  } else {
    o = (uint4){0u, 0u, 0u, 0u};
  }
  *(uint4*)(e16 + base) = o;
}

// ---------------------------------------------------------------------------
// DAG stage 0b: w1 [512,256] -> Bt [512][256] bf16 (P | Q split).
// ---------------------------------------------------------------------------
__global__ __launch_bounds__(256) void prep_w1T_pq(
    const float* __restrict__ w1, unsigned short* __restrict__ Bt) {
  int gid = blockIdx.x * 256 + threadIdx.x;  // 131072
  int n = gid >> 8, k = gid & 255;
  float v = (n < 256) ? w1[k * 256 + n] : w1[(256 + k) * 256 + (n - 256)];
  Bt[gid] = f2bf(v);
}

// ---------------------------------------------------------------------------
// DAG stage 2: s[r] = relu(P[leaf[r]] + Q[anc[r]] + b1) . w2
// ---------------------------------------------------------------------------
__global__ __launch_bounds__(256) void dag_score(
    const int* __restrict__ leaves, const int* __restrict__ anc,
    const unsigned short* __restrict__ PQ, const float* __restrict__ b1,
    const float* __restrict__ w2, float* __restrict__ s) {
  const int tid = threadIdx.x;
  const int l16 = tid & 15;
  const int r = blockIdx.x * 16 + (tid >> 4);

  float b1c[16], w2c[16];
#pragma unroll
  for (int j = 0; j < 4; ++j) {
    *(float4*)&b1c[j * 4] = *(const float4*)(b1 + l16 * 16 + j * 4);
    *(float4*)&w2c[j * 4] = *(const float4*)(w2 + l16 * 16 + j * 4);
  }

  const int nl = leaves[r], na = anc[r];
  const unsigned short* pp = PQ + (size_t)nl * 512 + l16 * 16;
  const unsigned short* qp = PQ + (size_t)na * 512 + 256 + l16 * 16;

  float acc = 0.f;
#pragma unroll
  for (int half = 0; half < 2; ++half) {
    uint4 pv = *(const uint4*)(pp + half * 8);
    uint4 qv = *(const uint4*)(qp + half * 8);
    const unsigned short* pu = (const unsigned short*)&pv;
    const unsigned short* qu = (const unsigned short*)&qv;
#pragma unroll
    for (int j = 0; j < 8; ++j) {
      float h = bf2f(pu[j]) + bf2f(qu[j]) + b1c[half * 8 + j];
      acc += fmaxf(h, 0.f) * w2c[half * 8 + j];
    }
  }
  acc += __shfl_xor(acc, 1, 64);
  acc += __shfl_xor(acc, 2, 64);
  acc += __shfl_xor(acc, 4, 64);
  acc += __shfl_xor(acc, 8, 64);
  if (l16 == 0) s[r] = acc;
}

// ---------------------------------------------------------------------------
// DAG stage 3: softmax over A=8, masked ancestor sum (bf16 emb) -> dict.
// ---------------------------------------------------------------------------
__global__ __launch_bounds__(256) void dag_finalize(
    const float* __restrict__ s, const float* __restrict__ masks,
    const int* __restrict__ anc, const float* __restrict__ b2,
    const unsigned short* __restrict__ emb16, float* __restrict__ dict) {
  const int c = blockIdx.x;
  const int t = threadIdx.x;
  __shared__ float sv[8], mv[8];
  __shared__ int nv[8];
  if (t < 8) {
    int idx = c * 8 + t;
    float m = masks[idx];
    sv[t] = s[idx] + b2[0] + (1.f - m) * VERY_NEG;
    mv[t] = m;
    nv[t] = anc[idx];
  }
  __syncthreads();
  float mx = -INFINITY;
#pragma unroll
  for (int a = 0; a < 8; ++a) mx = fmaxf(mx, sv[a]);
  float e[8], sum = 0.f;
#pragma unroll
  for (int a = 0; a < 8; ++a) { e[a] = __expf(sv[a] - mx); sum += e[a]; }
  float inv = 1.f / sum;
  float o = 0.f;
#pragma unroll
  for (int a = 0; a < 8; ++a)
    o += e[a] * inv * mv[a] * bf2f(emb16[(size_t)nv[a] * 256 + t]);
  dict[(size_t)(c + 1) * 256 + t] = o;
  if (c == 0) dict[t] = 0.f;
}

// ---------------------------------------------------------------------------
// Row gather -> fp32 AND bf16 (dual write; table read once).
// ---------------------------------------------------------------------------
__global__ __launch_bounds__(256) void gather_both(
    const int* __restrict__ ids, const float4* __restrict__ table,
    float4* __restrict__ outf, unsigned short* __restrict__ outb) {
  int gid = blockIdx.x * 256 + threadIdx.x;
  int row = gid >> 6;
  int c4 = gid & 63;
  float4 v = table[(size_t)ids[row] * 64 + c4];
  outf[gid] = v;
  uint2 o;
  o.x = pack2(v.x, v.y);
  o.y = pack2(v.z, v.w);
  *(uint2*)(outb + (size_t)gid * 4) = o;
}

// ---------------------------------------------------------------------------
// MFMA flash attention, v3: sum-via-ones-MFMA softmax, split-ks P buffer,
// swizzled LDS, 4 blocks/CU. (See round-3 notes.)
// ---------------------------------------------------------------------------
static __device__ __forceinline__ int vt_addr(int d, int col) {
  return d * 272 + ((((col) * 2) ^ (((d >> 3) & 3) << 4)) >> 1);
}
static __device__ __forceinline__ int ps_addr(int row, int col) {
  return row * 40 + ((((col) * 2) ^ (((row >> 2) & 3) << 4)) >> 1);
}

__global__ __launch_bounds__(256, 4) void attn_mfma(
    const unsigned short* __restrict__ q, const unsigned short* __restrict__ k,
    const unsigned short* __restrict__ v, const float* __restrict__ cm,
    unsigned short* __restrict__ ctx) {
  __shared__ unsigned short Vt[32 * 272];   // [d][seq], swizzled
  __shared__ unsigned short Ps[4][64 * 40]; // wave-private 64x32 P slab
  __shared__ float madd[256];
  const int b = blockIdx.x >> 3, h = blockIdx.x & 7;
  const int tid = threadIdx.x;
  const int wave = tid >> 6, lane = tid & 63;
  const int quad = lane >> 4, l15 = lane & 15;
  const size_t tokbase = (size_t)b * 256;
  const int hoff = h * 32;

  // V load + transpose (direct global -> scatter into swizzled Vt)
#pragma unroll
  for (int it = 0; it < 4; ++it) {
    int idx = tid + it * 256;
    int row = idx >> 2, c = idx & 3;
    uint4 w = *(const uint4*)(v + (tokbase + row) * 256 + hoff + c * 8);
    const unsigned short* wsp = (const unsigned short*)&w;
#pragma unroll
    for (int j = 0; j < 8; ++j) Vt[vt_addr(c * 8 + j, row)] = wsp[j];
  }
  madd[tid] = (1.f - cm[b * 256 + tid]) * VERY_NEG;
  __syncthreads();

  short8 qf[4];
#pragma unroll
  for (int mt = 0; mt < 4; ++mt) {
    size_t qrow = tokbase + wave * 64 + mt * 16 + l15;
    qf[mt] = *(const short8*)(q + qrow * 256 + hoff + quad * 8);
  }
  float madd_r[16];
#pragma unroll
  for (int nt = 0; nt < 16; ++nt) madd_r[nt] = madd[nt * 16 + l15];

  // constant ones-column B-fragment: B[k][0]=1, else 0.
  short8 vone;
#pragma unroll
  for (int j = 0; j < 8; ++j)
    ((unsigned short*)&vone)[j] = (l15 == 0) ? 0x3F80 : 0;

  floatx4 oa[4][2], oa_l[4];
#pragma unroll
  for (int mt = 0; mt < 4; ++mt) {
    oa_l[mt] = (floatx4){0.f, 0.f, 0.f, 0.f};
#pragma unroll
    for (int nd = 0; nd < 2; ++nd) oa[mt][nd] = (floatx4){0.f, 0.f, 0.f, 0.f};
  }

  const float scale = 0.17677669529663687f;  // 1/sqrt(32)
  unsigned short* Pw = &Ps[wave][0];

  for (int t = 0; t < 4; ++t) {
    // K fragments straight from global (L2-hit after first wave).
    short8 kf[4];
#pragma unroll
    for (int nt = 0; nt < 4; ++nt)
      kf[nt] = *(const short8*)(k + (tokbase + t * 64 + nt * 16 + l15) * 256 +
                                hoff + quad * 8);
    floatx4 sa[4][4];
#pragma unroll
    for (int mt = 0; mt < 4; ++mt)
#pragma unroll
      for (int nt = 0; nt < 4; ++nt) sa[mt][nt] = (floatx4){0.f, 0.f, 0.f, 0.f};
#pragma unroll
    for (int mt = 0; mt < 4; ++mt)
#pragma unroll
      for (int nt = 0; nt < 4; ++nt)
        sa[mt][nt] = __builtin_amdgcn_mfma_f32_16x16x32_bf16(
            qf[mt], kf[nt], sa[mt][nt], 0, 0, 0);

#pragma unroll
    for (int ks = 0; ks < 2; ++ks) {
      // exp + pack + write the 32-k slab (elementwise only).
#pragma unroll
      for (int mt = 0; mt < 4; ++mt)
#pragma unroll
        for (int n2 = 0; n2 < 2; ++n2) {
          int nt = ks * 2 + n2;
#pragma unroll
          for (int i = 0; i < 4; ++i) {
            float p = __expf(sa[mt][nt][i] * scale + madd_r[t * 4 + nt]);
            Pw[ps_addr(mt * 16 + quad * 4 + i, n2 * 16 + l15)] = f2bf(p);
          }
        }
      __asm__ __volatile__("s_waitcnt lgkmcnt(0)" ::: "memory");
      short8 vf[2];
#pragma unroll
      for (int nd = 0; nd < 2; ++nd)
        vf[nd] = *(const short8*)&Vt[vt_addr(nd * 16 + l15,
                                             t * 64 + ks * 32 + quad * 8)];
#pragma unroll
      for (int mt = 0; mt < 4; ++mt) {
        short8 pf = *(const short8*)&Pw[ps_addr(mt * 16 + l15, quad * 8)];
#pragma unroll
        for (int nd = 0; nd < 2; ++nd)
          oa[mt][nd] = __builtin_amdgcn_mfma_f32_16x16x32_bf16(
              pf, vf[nd], oa[mt][nd], 0, 0, 0);
        oa_l[mt] = __builtin_amdgcn_mfma_f32_16x16x32_bf16(
            pf, vone, oa_l[mt], 0, 0, 0);
      }
    }
  }

  // epilogue: broadcast row sums (held at l15==0 lanes), normalize, store.
  float inv[4][4];
#pragma unroll
  for (int mt = 0; mt < 4; ++mt)
#pragma unroll
    for (int i = 0; i < 4; ++i) {
      float l = __shfl(oa_l[mt][i], lane & 48, 64);
      inv[mt][i] = 1.f / l;
    }
#pragma unroll
  for (int mt = 0; mt < 4; ++mt)
#pragma unroll
    for (int nd = 0; nd < 2; ++nd)
#pragma unroll
      for (int i = 0; i < 4; ++i)
        Pw[ps_addr(mt * 16 + quad * 4 + i, nd * 16 + l15)] =
            f2bf(oa[mt][nd][i] * inv[mt][i]);
  __asm__ __volatile__("s_waitcnt lgkmcnt(0)" ::: "memory");
#pragma unroll
  for (int it = 0; it < 4; ++it) {
    int idx = it * 64 + lane;
    int row = idx >> 2, c = idx & 3;
    uint4 w = *(const uint4*)&Pw[ps_addr(row, c * 8)];
    *(uint4*)(ctx + (tokbase + wave * 64 + row) * 256 + hoff + c * 8) = w;
  }
}

// ---------------------------------------------------------------------------
// Attention pooling. 128 blocks x 512 thr.
// ---------------------------------------------------------------------------
__global__ __launch_bounds__(512) void pool_kernel(
    const float* __restrict__ x, const float* __restrict__ code_mask,
    const float* __restrict__ pw, const float* __restrict__ pb,
    float* __restrict__ out) {
  const int b = blockIdx.x;
  const int t = threadIdx.x;        // 0..511
  const int col = t & 255, half = t >> 8;
  __shared__ float ss[256];
  __shared__ float red[256];
  __shared__ float als[256];
  __shared__ float osum[512];
  const float* xb = x + (size_t)b * 256 * 256;

  if (t < 256) {
    float s = pb[0];
    for (int j = 0; j < 256; j += 4) {
      float4 xv = *(const float4*)(xb + (size_t)t * 256 + j);
      float4 wv = *(const float4*)(pw + j);
      s += xv.x * wv.x + xv.y * wv.y + xv.z * wv.z + xv.w * wv.w;
    }
    s += (1.f - code_mask[b * 256 + t]) * VERY_NEG;
    ss[t] = s; red[t] = s;
  }
  __syncthreads();
  for (int off = 128; off > 0; off >>= 1) {
    if (t < off) red[t] = fmaxf(red[t], red[t + off]);
    __syncthreads();
  }
  float m = red[0];
  __syncthreads();
  if (t < 256) {
    float e = __expf(ss[t] - m);
    als[t] = e; red[t] = e;
  }
  __syncthreads();
  for (int off = 128; off > 0; off >>= 1) {
    if (t < off) red[t] += red[t + off];
    __syncthreads();
  }
  float inv = 1.f / red[0];
  float o = 0.f;
  for (int si = half * 128; si < half * 128 + 128; ++si)
    o += als[si] * xb[(size_t)si * 256 + col];
  osum[t] = o;
  __syncthreads();
  if (t < 256) out[b * 256 + t] = (osum[t] + osum[t + 256]) * inv;
}

// ---------------------------------------------------------------------------
extern "C" void kernel_launch(void* const* d_in, const int* in_sizes, int n_in,
                              void* d_out, int out_size, void* d_ws,
                              size_t ws_size, hipStream_t stream) {
  const int* input_ids = (const int*)d_in[0];
  const float* code_mask = (const float*)d_in[1];
  const int* dx_leaves = (const int*)d_in[2];
  const int* dx_anc = (const int*)d_in[3];
  const float* dx_masks = (const float*)d_in[4];
  const float* embed_init_w = (const float*)d_in[5];
  const float* embed_inputs_w = (const float*)d_in[6];
  const float* attn_w1 = (const float*)d_in[7];
  const float* attn_b1 = (const float*)d_in[8];
  const float* attn_w2 = (const float*)d_in[9];
  const float* attn_b2 = (const float*)d_in[10];
  const float* pool_w = (const float*)d_in[11];
  const float* pool_b = (const float*)d_in[12];

  float* out = (float*)d_out;
  float* ws = (float*)d_ws;

  // workspace layout (floats)
  float* dict = ws;                      // 5,120,256
  float* xbuf = dict + 5120256;          // 8,388,608
  float* qb   = xbuf + 8388608;          // 8,388,608
  float* kb   = qb + 8388608;            // 8,388,608
  float* vb   = kb + 8388608;            // 8,388,608
  float* ctxb = vb + 8388608;            // 8,388,608
  float* wend = ctxb + 8388608;          // weight area (393,216 floats)

  // DAG-phase aliases over regions dead until the encoder phase:
  unsigned short* emb16  = (unsigned short*)xbuf;             // 6,422,528 ush
  unsigned short* pq16   = (unsigned short*)(xbuf + 3211264); // 12,845,056 ush (spills into qb)
  unsigned short* w1T_pq = (unsigned short*)kb;               // 131,072 ush
  float* sbuf = vb;                                           // 160,000 floats

  // encoder-phase aliases:
  unsigned short* xb16  = (unsigned short*)ctxb;  // bf16(x) pre-QKV, later ctx
  unsigned short* qkv16 = (unsigned short*)qb;    // q/k/v bf16, 16777216 stride
  unsigned short* xq16  = (unsigned short*)qb;    // bf16(x) post-WO (q dead)
  // bf16 weights:
  unsigned short* qkvT = (unsigned short*)wend;   // 196,608
  unsigned short* woT  = qkvT + 196608;           // 65,536
  unsigned short* fw1T = woT + 65536;             // 262,144
  unsigned short* fw2T = fw1T + 262144;           // 262,144

  // 1) DAG embedding -> dict_matrix (factored PQ path).
  cvt_emb16<<<3136, 256, 0, stream>>>(embed_init_w, emb16);
  prep_w1T_pq<<<512, 256, 0, stream>>>(attn_w1, w1T_pq);
  gemm_mfma<256, false, false, false, 1><<<dim3(4, 196), 256, 0, stream>>>(
      emb16, w1T_pq, nullptr, nullptr, nullptr, pq16, 512);
  dag_score<<<Rc / 16, 256, 0, stream>>>(dx_leaves, dx_anc, pq16, attn_b1,
                                         attn_w2, sbuf);
  dag_finalize<<<Cc, 256, 0, stream>>>(sbuf, dx_masks, dx_anc, attn_b2,
                                       emb16, dict);

  auto run_encoder = [&](const float* wq, const float* wk, const float* wv,
                         const float* wo, const float* fw1, const float* fb1,
                         const float* fw2, const float* fb2, float* final_out) {
    prep_weights<<<192, 256, 0, stream>>>(wq, wk, wv, wo, fw1, fw2, qkvT,
                                          woT, fw1T, fw2T);
    // fused QKV: N=768, bf16 split-output into q/k/v buffers
    gemm_mfma<256, false, false, false, 3><<<dim3(6, 256), 256, 0, stream>>>(
        xb16, qkvT, nullptr, nullptr, nullptr, qkv16, 256);
    // MFMA flash attention -> bf16 ctx (into xb16 region; dead post-QKV)
    attn_mfma<<<Bc * NHc, 256, 0, stream>>>(qkv16, qkv16 + 16777216,
                                            qkv16 + 33554432, code_mask, xb16);
    // x += ctx @ wo  (fp32 resid out to xbuf, bf16 copy to xq16)
    gemm_mfma<256, false, false, true, 2><<<dim3(2, 256), 256, 0, stream>>>(
        xb16, woT, nullptr, xbuf, xbuf, xq16, 256);
    // fused FFN v3: 128-row panels, 512 thr, x-in-registers, 1 block/CU
    ffn_fused<<<256, 512, 0, stream>>>(xq16, fw1T, fw2T, fb1, fb2, xbuf,
                                       final_out);
  };

  // 2) visit stream
  gather_both<<<8192, 256, 0, stream>>>(input_ids,
                                        (const float4*)embed_inputs_w,
                                        (float4*)xbuf, xb16);
  run_encoder((const float*)d_in[13], (const float*)d_in[14],
              (const float*)d_in[15], (const float*)d_in[16],
              (const float*)d_in[17], (const float*)d_in[18],
              (const float*)d_in[19], (const float*)d_in[20], out);

  // 3) dag stream
  gather_both<<<8192, 256, 0, stream>>>(input_ids, (const float4*)dict,
                                        (float4*)xbuf, xb16);
  run_encoder((const float*)d_in[21], (const float*)d_in[22],
              (const float*)d_in[23], (const float*)d_in[24],
              (const float*)d_in[25], (const float*)d_in[26],
              (const float*)d_in[27], (const float*)d_in[28], xbuf);

  pool_kernel<<<Bc, 512, 0, stream>>>(xbuf, code_mask, pool_w, pool_b,
                                      out + 8388608);
}

// Round 8
// 552.874 us; speedup vs baseline: 1.0261x; 1.0060x over previous
//
#include <hip/hip_runtime.h>
#include <hip/hip_bf16.h>
#include <math.h>

#define VERY_NEG (-1e30f)

// B=128, S=256, H=256, C=20000, NODES=25000, A=8, NH=8, d=32, FF=1024
constexpr int Bc = 128, Sc = 256, Hc = 256, Cc = 20000, Ac = 8, NHc = 8, DHc = 32, FFc = 1024;
constexpr int Mc = Bc * Sc;  // 32768 rows
constexpr int Rc = Cc * Ac;  // 160000 dag rows

typedef __attribute__((ext_vector_type(8))) short short8;
typedef __attribute__((ext_vector_type(4))) float floatx4;

static __device__ __forceinline__ unsigned short f2bf(float f) {
  union { float f; unsigned u; } v; v.f = f;
  unsigned r = v.u + 0x7FFF + ((v.u >> 16) & 1);   // RNE
  return (unsigned short)(r >> 16);
}
static __device__ __forceinline__ unsigned pack2(float lo, float hi) {
  return (unsigned)f2bf(lo) | ((unsigned)f2bf(hi) << 16);
}
static __device__ __forceinline__ float bf2f(unsigned short u) {
  union { unsigned u; float f; } v; v.u = ((unsigned)u) << 16; return v.f;
}

// async global->LDS, 16B per lane; lane i lands at base + i*16.
static __device__ __forceinline__ void glds16(const unsigned short* g,
                                              unsigned short* l) {
  __builtin_amdgcn_global_load_lds(
      (const __attribute__((address_space(1))) void*)g,
      (__attribute__((address_space(3))) void*)l, 16, 0, 0);
}

// ---------------------------------------------------------------------------
// Per-layer weight prep v2: 64x64 LDS-tile transpose, coalesced both sides.
// Tile map: blk 0-47 wq/wk/wv -> qkvT, 48-63 wo -> woT,
//           64-127 fw1 [256][1024] -> fw1T, 128-191 fw2 [1024][256] -> fw2T.
// ---------------------------------------------------------------------------
__global__ __launch_bounds__(256) void prep_weights(
    const float* __restrict__ wq, const float* __restrict__ wk,
    const float* __restrict__ wv, const float* __restrict__ wo,
    const float* __restrict__ fw1, const float* __restrict__ fw2,
    unsigned short* __restrict__ qkvT, unsigned short* __restrict__ woT,
    unsigned short* __restrict__ fw1T, unsigned short* __restrict__ fw2T) {
  __shared__ float T[64][65];
  const int t = blockIdx.x;
  const float* src;
  unsigned short* dst;
  int R, Cn, tr, tc;
  if (t < 64) {  // 256x256 matrices, 16 tiles each
    int m = t >> 4, tt = t & 15;
    src = m == 0 ? wq : (m == 1 ? wk : (m == 2 ? wv : wo));
    dst = m < 3 ? qkvT + m * 65536 : woT;
    R = 256; Cn = 256; tr = tt >> 2; tc = tt & 3;
  } else if (t < 128) {  // fw1 [256][1024]
    int tt = t - 64;
    src = fw1; dst = fw1T; R = 256; Cn = 1024;
    tr = tt >> 4; tc = tt & 15;
  } else {               // fw2 [1024][256]
    int tt = t - 128;
    src = fw2; dst = fw2T; R = 1024; Cn = 256;
    tr = tt >> 2; tc = tt & 3;
  }
  const int r0 = threadIdx.x >> 4, c4 = threadIdx.x & 15;
#pragma unroll
  for (int it = 0; it < 4; ++it) {
    int row = it * 16 + r0;
    *(float4*)&T[row][c4 * 4] =
        *(const float4*)(src + (size_t)(tr * 64 + row) * Cn + tc * 64 + c4 * 4);
  }
  __syncthreads();
  const int c0 = threadIdx.x >> 2, seg = threadIdx.x & 3;
  unsigned short tmp[16];
#pragma unroll
  for (int j = 0; j < 16; ++j) tmp[j] = f2bf(T[seg * 16 + j][c0]);
  unsigned short* dp = dst + (size_t)(tc * 64 + c0) * R + tr * 64 + seg * 16;
  *(uint4*)dp = *(uint4*)&tmp[0];
  *(uint4*)(dp + 8) = *(uint4*)&tmp[8];
}

// ---------------------------------------------------------------------------
// bf16 MFMA GEMM, glds staging, BK=64, XOR-swizzled unpadded LDS [128][64].
// XCD-aware bijective blockIdx swizzle (all launches have nwg%8==0).
// OUT: 0 fp32->Cf; 1 bf16->C2; 2 both; 3 bf16 QKV split (col>>8 buffer).
// ---------------------------------------------------------------------------
template <int K, bool BIAS, bool RELU, bool RESID, int OUT>
__global__ __launch_bounds__(256) void gemm_mfma(
    const unsigned short* __restrict__ A, const unsigned short* __restrict__ Bt,
    const float* __restrict__ bias, const float* __restrict__ resid,
    float* __restrict__ Cf, unsigned short* __restrict__ C2, int N) {
  __shared__ unsigned short As[128 * 64];
  __shared__ unsigned short Bs[128 * 64];
  const int tid = threadIdx.x;
  const int nwg = gridDim.x * gridDim.y;
  const int bid0 = blockIdx.y * gridDim.x + blockIdx.x;
  const int swz = (bid0 & 7) * (nwg >> 3) + (bid0 >> 3);
  const int rowBase = (swz / gridDim.x) * 128;
  const int colBase = (swz % gridDim.x) * 128;
  const int wave = tid >> 6, lane = tid & 63;
  const int wm = wave >> 1, wn = wave & 1;
  const int quad = lane >> 4, l15 = lane & 15;
  const int s8 = (((lane & 7) ^ (lane >> 3)) << 3);  // swizzled global chunk
  const int rs0 = (wave << 5) + (lane >> 3);         // staged row base
  const int swzf = l15 & 7;

  floatx4 acc[4][4];
#pragma unroll
  for (int mt = 0; mt < 4; ++mt)
#pragma unroll
    for (int nt = 0; nt < 4; ++nt) acc[mt][nt] = (floatx4){0.f, 0.f, 0.f, 0.f};

  for (int k0 = 0; k0 < K; k0 += 64) {
#pragma unroll
    for (int i = 0; i < 4; ++i) {
      int r = rs0 + (i << 3);
      int lb = wave * 2048 + i * 512;
      glds16(A + (size_t)(rowBase + r) * K + k0 + s8, &As[lb]);
      glds16(Bt + (size_t)(colBase + r) * K + k0 + s8, &Bs[lb]);
    }
    __syncthreads();
#pragma unroll
    for (int kk = 0; kk < 2; ++kk) {
      short8 af[4], bfr[4];
#pragma unroll
      for (int mt = 0; mt < 4; ++mt)
        af[mt] = *(const short8*)&As[(wm * 64 + mt * 16 + l15) * 64 +
                                     ((((kk << 2) | quad) ^ swzf) << 3)];
#pragma unroll
      for (int nt = 0; nt < 4; ++nt)
        bfr[nt] = *(const short8*)&Bs[(wn * 64 + nt * 16 + l15) * 64 +
                                      ((((kk << 2) | quad) ^ swzf) << 3)];
#pragma unroll
      for (int mt = 0; mt < 4; ++mt)
#pragma unroll
        for (int nt = 0; nt < 4; ++nt)
          acc[mt][nt] = __builtin_amdgcn_mfma_f32_16x16x32_bf16(
              af[mt], bfr[nt], acc[mt][nt], 0, 0, 0);
    }
    __syncthreads();
  }

#pragma unroll
  for (int mt = 0; mt < 4; ++mt) {
#pragma unroll
    for (int nt = 0; nt < 4; ++nt) {
      int col = colBase + wn * 64 + nt * 16 + l15;
      float bz = BIAS ? bias[col] : 0.f;
#pragma unroll
      for (int i = 0; i < 4; ++i) {
        int row = rowBase + wm * 64 + mt * 16 + quad * 4 + i;
        float v = acc[mt][nt][i];
        if (BIAS) v += bz;
        if (RELU) v = fmaxf(v, 0.f);
        if (RESID) v += resid[(size_t)row * N + col];
        if (OUT == 0) {
          Cf[(size_t)row * N + col] = v;
        } else if (OUT == 1) {
          C2[(size_t)row * N + col] = f2bf(v);
        } else if (OUT == 2) {
          Cf[(size_t)row * N + col] = v;
          C2[(size_t)row * N + col] = f2bf(v);
        } else {  // QKV split
          C2[(size_t)(col >> 8) * 16777216 + (size_t)row * 256 + (col & 255)] =
              f2bf(v);
        }
      }
    }
  }
}

// ---------------------------------------------------------------------------
// DAG stage 0a: embed_init_w [25001][256] fp32 -> emb16 [25088][256] bf16
// ---------------------------------------------------------------------------
__global__ __launch_bounds__(256) void cvt_emb16(
    const float* __restrict__ emb, unsigned short* __restrict__ e16) {
  int gid = blockIdx.x * 256 + threadIdx.x;  // 802816 threads, 8 elems each
  int base = gid * 8;
  int row = base >> 8;
  uint4 o;
  if (row < 25001) {
    float4 a = *(const float4*)(emb + base);
    float4 b = *(const float4*)(emb + base + 4);
    o.x = pack2(a.x, a.y); o.y = pack2(a.z, a.w);
    o.z = pack2(b.x, b.y); o.w = pack2(b.z, b.w);
  } else {
    o = (uint4){0u, 0u, 0u, 0u};
  }
  *(uint4*)(e16 + base) = o;
}

// ---------------------------------------------------------------------------
// DAG stage 0b: w1 [512,256] -> Bt [512][256] bf16 (P | Q split).
// ---------------------------------------------------------------------------
__global__ __launch_bounds__(256) void prep_w1T_pq(
    const float* __restrict__ w1, unsigned short* __restrict__ Bt) {
  int gid = blockIdx.x * 256 + threadIdx.x;  // 131072
  int n = gid >> 8, k = gid & 255;
  float v = (n < 256) ? w1[k * 256 + n] : w1[(256 + k) * 256 + (n - 256)];
  Bt[gid] = f2bf(v);
}

// ---------------------------------------------------------------------------
// DAG fused score+softmax+gather: one block per code.
// Score phase: group a = t>>5 (8 rows), lane l32 = t&31 handles 8 hidden
// elems; s[a] = relu(P[leaf]+Q[anc]+b1).w2 via width-32 shuffle reduce.
// Then in-block softmax over A=8 and masked bf16 ancestor gather -> dict.
// Replaces dag_score + dag_finalize (one launch, no sbuf round-trip).
// ---------------------------------------------------------------------------
__global__ __launch_bounds__(256) void dag_fused(
    const int* __restrict__ leaves, const int* __restrict__ anc,
    const unsigned short* __restrict__ PQ, const float* __restrict__ b1,
    const float* __restrict__ w2, const float* __restrict__ b2,
    const float* __restrict__ masks, const unsigned short* __restrict__ emb16,
    float* __restrict__ dict) {
  const int c = blockIdx.x;
  const int t = threadIdx.x;
  const int a = t >> 5, l32 = t & 31;
  __shared__ float sv[8], mv[8];
  __shared__ int nv[8];

  // ---- score ----
  float b1c[8], w2c[8];
  *(float4*)&b1c[0] = *(const float4*)(b1 + l32 * 8);
  *(float4*)&b1c[4] = *(const float4*)(b1 + l32 * 8 + 4);
  *(float4*)&w2c[0] = *(const float4*)(w2 + l32 * 8);
  *(float4*)&w2c[4] = *(const float4*)(w2 + l32 * 8 + 4);
  const int idx = c * 8 + a;
  const int nl = leaves[idx], na = anc[idx];
  uint4 pv = *(const uint4*)(PQ + (size_t)nl * 512 + l32 * 8);
  uint4 qv = *(const uint4*)(PQ + (size_t)na * 512 + 256 + l32 * 8);
  const unsigned short* pu = (const unsigned short*)&pv;
  const unsigned short* qu = (const unsigned short*)&qv;
  float acc = 0.f;
#pragma unroll
  for (int j = 0; j < 8; ++j) {
    float h = bf2f(pu[j]) + bf2f(qu[j]) + b1c[j];
    acc += fmaxf(h, 0.f) * w2c[j];
  }
  acc += __shfl_xor(acc, 1, 32);
  acc += __shfl_xor(acc, 2, 32);
  acc += __shfl_xor(acc, 4, 32);
  acc += __shfl_xor(acc, 8, 32);
  acc += __shfl_xor(acc, 16, 32);
  if (l32 == 0) {
    float m = masks[idx];
    sv[a] = acc + b2[0] + (1.f - m) * VERY_NEG;
    mv[a] = m;
    nv[a] = na;
  }
  __syncthreads();

  // ---- softmax + masked ancestor gather (t = output column) ----
  float mx = -INFINITY;
#pragma unroll
  for (int aa = 0; aa < 8; ++aa) mx = fmaxf(mx, sv[aa]);
  float e[8], sum = 0.f;
#pragma unroll
  for (int aa = 0; aa < 8; ++aa) { e[aa] = __expf(sv[aa] - mx); sum += e[aa]; }
  float inv = 1.f / sum;
  float o = 0.f;
#pragma unroll
  for (int aa = 0; aa < 8; ++aa)
    o += e[aa] * inv * mv[aa] * bf2f(emb16[(size_t)nv[aa] * 256 + t]);
  dict[(size_t)(c + 1) * 256 + t] = o;
  if (c == 0) dict[t] = 0.f;
}

// ---------------------------------------------------------------------------
// Row gather -> fp32 AND bf16 (dual write; table read once).
// ---------------------------------------------------------------------------
__global__ __launch_bounds__(256) void gather_both(
    const int* __restrict__ ids, const float4* __restrict__ table,
    float4* __restrict__ outf, unsigned short* __restrict__ outb) {
  int gid = blockIdx.x * 256 + threadIdx.x;
  int row = gid >> 6;
  int c4 = gid & 63;
  float4 v = table[(size_t)ids[row] * 64 + c4];
  outf[gid] = v;
  uint2 o;
  o.x = pack2(v.x, v.y);
  o.y = pack2(v.z, v.w);
  *(uint2*)(outb + (size_t)gid * 4) = o;
}

// ---------------------------------------------------------------------------
// MFMA flash attention, v3: sum-via-ones-MFMA softmax, split-ks P buffer,
// swizzled LDS, 4 blocks/CU. (See round-3 notes.)
// ---------------------------------------------------------------------------
static __device__ __forceinline__ int vt_addr(int d, int col) {
  return d * 272 + ((((col) * 2) ^ (((d >> 3) & 3) << 4)) >> 1);
}
static __device__ __forceinline__ int ps_addr(int row, int col) {
  return row * 40 + ((((col) * 2) ^ (((row >> 2) & 3) << 4)) >> 1);
}

__global__ __launch_bounds__(256, 4) void attn_mfma(
    const unsigned short* __restrict__ q, const unsigned short* __restrict__ k,
    const unsigned short* __restrict__ v, const float* __restrict__ cm,
    unsigned short* __restrict__ ctx) {
  __shared__ unsigned short Vt[32 * 272];   // [d][seq], swizzled
  __shared__ unsigned short Ps[4][64 * 40]; // wave-private 64x32 P slab
  __shared__ float madd[256];
  const int b = blockIdx.x >> 3, h = blockIdx.x & 7;
  const int tid = threadIdx.x;
  const int wave = tid >> 6, lane = tid & 63;
  const int quad = lane >> 4, l15 = lane & 15;
  const size_t tokbase = (size_t)b * 256;
  const int hoff = h * 32;

  // V load + transpose (direct global -> scatter into swizzled Vt)
#pragma unroll
  for (int it = 0; it < 4; ++it) {
    int idx = tid + it * 256;
    int row = idx >> 2, c = idx & 3;
    uint4 w = *(const uint4*)(v + (tokbase + row) * 256 + hoff + c * 8);
    const unsigned short* wsp = (const unsigned short*)&w;
#pragma unroll
    for (int j = 0; j < 8; ++j) Vt[vt_addr(c * 8 + j, row)] = wsp[j];
  }
  madd[tid] = (1.f - cm[b * 256 + tid]) * VERY_NEG;
  __syncthreads();

  short8 qf[4];
#pragma unroll
  for (int mt = 0; mt < 4; ++mt) {
    size_t qrow = tokbase + wave * 64 + mt * 16 + l15;
    qf[mt] = *(const short8*)(q + qrow * 256 + hoff + quad * 8);
  }
  float madd_r[16];
#pragma unroll
  for (int nt = 0; nt < 16; ++nt) madd_r[nt] = madd[nt * 16 + l15];

  // constant ones-column B-fragment: B[k][0]=1, else 0.
  short8 vone;
#pragma unroll
  for (int j = 0; j < 8; ++j)
    ((unsigned short*)&vone)[j] = (l15 == 0) ? 0x3F80 : 0;

  floatx4 oa[4][2], oa_l[4];
#pragma unroll
  for (int mt = 0; mt < 4; ++mt) {
    oa_l[mt] = (floatx4){0.f, 0.f, 0.f, 0.f};
#pragma unroll
    for (int nd = 0; nd < 2; ++nd) oa[mt][nd] = (floatx4){0.f, 0.f, 0.f, 0.f};
  }

  const float scale = 0.17677669529663687f;  // 1/sqrt(32)
  unsigned short* Pw = &Ps[wave][0];

  for (int t = 0; t < 4; ++t) {
    // K fragments straight from global (L2-hit after first wave).
    short8 kf[4];
#pragma unroll
    for (int nt = 0; nt < 4; ++nt)
      kf[nt] = *(const short8*)(k + (tokbase + t * 64 + nt * 16 + l15) * 256 +
                                hoff + quad * 8);
    floatx4 sa[4][4];
#pragma unroll
    for (int mt = 0; mt < 4; ++mt)
#pragma unroll
      for (int nt = 0; nt < 4; ++nt) sa[mt][nt] = (floatx4){0.f, 0.f, 0.f, 0.f};
#pragma unroll
    for (int mt = 0; mt < 4; ++mt)
#pragma unroll
      for (int nt = 0; nt < 4; ++nt)
        sa[mt][nt] = __builtin_amdgcn_mfma_f32_16x16x32_bf16(
            qf[mt], kf[nt], sa[mt][nt], 0, 0, 0);

#pragma unroll
    for (int ks = 0; ks < 2; ++ks) {
      // exp + pack + write the 32-k slab (elementwise only).
#pragma unroll
      for (int mt = 0; mt < 4; ++mt)
#pragma unroll
        for (int n2 = 0; n2 < 2; ++n2) {
          int nt = ks * 2 + n2;
#pragma unroll
          for (int i = 0; i < 4; ++i) {
            float p = __expf(sa[mt][nt][i] * scale + madd_r[t * 4 + nt]);
            Pw[ps_addr(mt * 16 + quad * 4 + i, n2 * 16 + l15)] = f2bf(p);
          }
        }
      __asm__ __volatile__("s_waitcnt lgkmcnt(0)" ::: "memory");
      short8 vf[2];
#pragma unroll
      for (int nd = 0; nd < 2; ++nd)
        vf[nd] = *(const short8*)&Vt[vt_addr(nd * 16 + l15,
                                             t * 64 + ks * 32 + quad * 8)];
#pragma unroll
      for (int mt = 0; mt < 4; ++mt) {
        short8 pf = *(const short8*)&Pw[ps_addr(mt * 16 + l15, quad * 8)];
#pragma unroll
        for (int nd = 0; nd < 2; ++nd)
          oa[mt][nd] = __builtin_amdgcn_mfma_f32_16x16x32_bf16(
              pf, vf[nd], oa[mt][nd], 0, 0, 0);
        oa_l[mt] = __builtin_amdgcn_mfma_f32_16x16x32_bf16(
            pf, vone, oa_l[mt], 0, 0, 0);
      }
    }
  }

  // epilogue: broadcast row sums (held at l15==0 lanes), normalize, store.
  float inv[4][4];
#pragma unroll
  for (int mt = 0; mt < 4; ++mt)
#pragma unroll
    for (int i = 0; i < 4; ++i) {
      float l = __shfl(oa_l[mt][i], lane & 48, 64);
      inv[mt][i] = 1.f / l;
    }
#pragma unroll
  for (int mt = 0; mt < 4; ++mt)
#pragma unroll
    for (int nd = 0; nd < 2; ++nd)
#pragma unroll
      for (int i = 0; i < 4; ++i)
        Pw[ps_addr(mt * 16 + quad * 4 + i, nd * 16 + l15)] =
            f2bf(oa[mt][nd][i] * inv[mt][i]);
  __asm__ __volatile__("s_waitcnt lgkmcnt(0)" ::: "memory");
#pragma unroll
  for (int it = 0; it < 4; ++it) {
    int idx = it * 64 + lane;
    int row = idx >> 2, c = idx & 3;
    uint4 w = *(const uint4*)&Pw[ps_addr(row, c * 8)];
    *(uint4*)(ctx + (tokbase + wave * 64 + row) * 256 + hoff + c * 8) = w;
  }
}

// ---------------------------------------------------------------------------
// Attention pooling. 128 blocks x 512 thr.
// ---------------------------------------------------------------------------
__global__ __launch_bounds__(512) void pool_kernel(
    const float* __restrict__ x, const float* __restrict__ code_mask,
    const float* __restrict__ pw, const float* __restrict__ pb,
    float* __restrict__ out) {
  const int b = blockIdx.x;
  const int t = threadIdx.x;        // 0..511
  const int col = t & 255, half = t >> 8;
  __shared__ float ss[256];
  __shared__ float red[256];
  __shared__ float als[256];
  __shared__ float osum[512];
  const float* xb = x + (size_t)b * 256 * 256;

  if (t < 256) {
    float s = pb[0];
    for (int j = 0; j < 256; j += 4) {
      float4 xv = *(const float4*)(xb + (size_t)t * 256 + j);
      float4 wv = *(const float4*)(pw + j);
      s += xv.x * wv.x + xv.y * wv.y + xv.z * wv.z + xv.w * wv.w;
    }
    s += (1.f - code_mask[b * 256 + t]) * VERY_NEG;
    ss[t] = s; red[t] = s;
  }
  __syncthreads();
  for (int off = 128; off > 0; off >>= 1) {
    if (t < off) red[t] = fmaxf(red[t], red[t + off]);
    __syncthreads();
  }
  float m = red[0];
  __syncthreads();
  if (t < 256) {
    float e = __expf(ss[t] - m);
    als[t] = e; red[t] = e;
  }
  __syncthreads();
  for (int off = 128; off > 0; off >>= 1) {
    if (t < off) red[t] += red[t + off];
    __syncthreads();
  }
  float inv = 1.f / red[0];
  float o = 0.f;
  for (int si = half * 128; si < half * 128 + 128; ++si)
    o += als[si] * xb[(size_t)si * 256 + col];
  osum[t] = o;
  __syncthreads();
  if (t < 256) out[b * 256 + t] = (osum[t] + osum[t + 256]) * inv;
}

// ---------------------------------------------------------------------------
extern "C" void kernel_launch(void* const* d_in, const int* in_sizes, int n_in,
                              void* d_out, int out_size, void* d_ws,
                              size_t ws_size, hipStream_t stream) {
  const int* input_ids = (const int*)d_in[0];
  const float* code_mask = (const float*)d_in[1];
  const int* dx_leaves = (const int*)d_in[2];
  const int* dx_anc = (const int*)d_in[3];
  const float* dx_masks = (const float*)d_in[4];
  const float* embed_init_w = (const float*)d_in[5];
  const float* embed_inputs_w = (const float*)d_in[6];
  const float* attn_w1 = (const float*)d_in[7];
  const float* attn_b1 = (const float*)d_in[8];
  const float* attn_w2 = (const float*)d_in[9];
  const float* attn_b2 = (const float*)d_in[10];
  const float* pool_w = (const float*)d_in[11];
  const float* pool_b = (const float*)d_in[12];

  float* out = (float*)d_out;
  float* ws = (float*)d_ws;

  // workspace layout (floats)
  float* dict = ws;                      // 5,120,256
  float* xbuf = dict + 5120256;          // 8,388,608
  float* qb   = xbuf + 8388608;          // 8,388,608
  float* kb   = qb + 8388608;            // 8,388,608
  float* vb   = kb + 8388608;            // 8,388,608
  float* ctxb = vb + 8388608;            // 8,388,608
  float* wend = ctxb + 8388608;          // weight area (393,216 floats)

  // DAG-phase aliases over regions dead until the encoder phase:
  unsigned short* emb16  = (unsigned short*)xbuf;             // 6,422,528 ush
  unsigned short* pq16   = (unsigned short*)(xbuf + 3211264); // 12,845,056 ush (spills into qb)
  unsigned short* w1T_pq = (unsigned short*)kb;               // 131,072 ush

  // encoder-phase aliases:
  unsigned short* xb16  = (unsigned short*)ctxb;  // bf16(x) pre-QKV, later ctx
  unsigned short* qkv16 = (unsigned short*)qb;    // q/k/v bf16, 16777216 stride
  unsigned short* xq16  = (unsigned short*)qb;    // bf16(x) post-WO (q dead)
  unsigned short* hid16 = (unsigned short*)kb;    // FFN hidden [32768][1024] (k+v)
  // bf16 weights:
  unsigned short* qkvT = (unsigned short*)wend;   // 196,608
  unsigned short* woT  = qkvT + 196608;           // 65,536
  unsigned short* fw1T = woT + 65536;             // 262,144
  unsigned short* fw2T = fw1T + 262144;           // 262,144

  // 1) DAG embedding -> dict_matrix (factored PQ path, fused score+finalize).
  cvt_emb16<<<3136, 256, 0, stream>>>(embed_init_w, emb16);
  prep_w1T_pq<<<512, 256, 0, stream>>>(attn_w1, w1T_pq);
  gemm_mfma<256, false, false, false, 1><<<dim3(4, 196), 256, 0, stream>>>(
      emb16, w1T_pq, nullptr, nullptr, nullptr, pq16, 512);
  dag_fused<<<Cc, 256, 0, stream>>>(dx_leaves, dx_anc, pq16, attn_b1, attn_w2,
                                    attn_b2, dx_masks, emb16, dict);

  auto run_encoder = [&](const float* wq, const float* wk, const float* wv,
                         const float* wo, const float* fw1, const float* fb1,
                         const float* fw2, const float* fb2, float* final_out) {
    prep_weights<<<192, 256, 0, stream>>>(wq, wk, wv, wo, fw1, fw2, qkvT,
                                          woT, fw1T, fw2T);
    // fused QKV: N=768, bf16 split-output into q/k/v buffers
    gemm_mfma<256, false, false, false, 3><<<dim3(6, 256), 256, 0, stream>>>(
        xb16, qkvT, nullptr, nullptr, nullptr, qkv16, 256);
    // MFMA flash attention -> bf16 ctx (into xb16 region; dead post-QKV)
    attn_mfma<<<Bc * NHc, 256, 0, stream>>>(qkv16, qkv16 + 16777216,
                                            qkv16 + 33554432, code_mask, xb16);
    // x += ctx @ wo  (fp32 resid out to xbuf, bf16 copy to xq16)
    gemm_mfma<256, false, false, true, 2><<<dim3(2, 256), 256, 0, stream>>>(
        xb16, woT, nullptr, xbuf, xbuf, xq16, 256);
    // FFN (split pair: best-measured config; hid16 is L3-resident)
    gemm_mfma<256, true, true, false, 1><<<dim3(8, 256), 256, 0, stream>>>(
        xq16, fw1T, fb1, nullptr, nullptr, hid16, 1024);
    gemm_mfma<1024, true, false, true, 0><<<dim3(2, 256), 256, 0, stream>>>(
        hid16, fw2T, fb2, xbuf, final_out, nullptr, 256);
  };

  // 2) visit stream
  gather_both<<<8192, 256, 0, stream>>>(input_ids,
                                        (const float4*)embed_inputs_w,
                                        (float4*)xbuf, xb16);
  run_encoder((const float*)d_in[13], (const float*)d_in[14],
              (const float*)d_in[15], (const float*)d_in[16],
              (const float*)d_in[17], (const float*)d_in[18],
              (const float*)d_in[19], (const float*)d_in[20], out);

  // 3) dag stream
  gather_both<<<8192, 256, 0, stream>>>(input_ids, (const float4*)dict,
                                        (float4*)xbuf, xb16);
  run_encoder((const float*)d_in[21], (const float*)d_in[22],
              (const float*)d_in[23], (const float*)d_in[24],
              (const float*)d_in[25], (const float*)d_in[26],
              (const float*)d_in[27], (const float*)d_in[28], xbuf);

  pool_kernel<<<Bc, 512, 0, stream>>>(xbuf, code_mask, pool_w, pool_b,
                                      out + 8388608);
}

// Round 9
// 534.938 us; speedup vs baseline: 1.0605x; 1.0335x over previous
//
#include <hip/hip_runtime.h>
#include <hip/hip_bf16.h>
#include <math.h>

#define VERY_NEG (-1e30f)

// B=128, S=256, H=256, C=20000, NODES=25000, A=8, NH=8, d=32, FF=1024
constexpr int Bc = 128, Sc = 256, Hc = 256, Cc = 20000, Ac = 8, NHc = 8, DHc = 32, FFc = 1024;
constexpr int Mc = Bc * Sc;  // 32768 rows
constexpr int Rc = Cc * Ac;  // 160000 dag rows

typedef __attribute__((ext_vector_type(8))) short short8;
typedef __attribute__((ext_vector_type(4))) float floatx4;

static __device__ __forceinline__ unsigned short f2bf(float f) {
  union { float f; unsigned u; } v; v.f = f;
  unsigned r = v.u + 0x7FFF + ((v.u >> 16) & 1);   // RNE
  return (unsigned short)(r >> 16);
}
static __device__ __forceinline__ unsigned pack2(float lo, float hi) {
  return (unsigned)f2bf(lo) | ((unsigned)f2bf(hi) << 16);
}
static __device__ __forceinline__ float bf2f(unsigned short u) {
  union { unsigned u; float f; } v; v.u = ((unsigned)u) << 16; return v.f;
}

// async global->LDS, 16B per lane; lane i lands at base + i*16.
static __device__ __forceinline__ void glds16(const unsigned short* g,
                                              unsigned short* l) {
  __builtin_amdgcn_global_load_lds(
      (const __attribute__((address_space(1))) void*)g,
      (__attribute__((address_space(3))) void*)l, 16, 0, 0);
}

// ---------------------------------------------------------------------------
// Per-layer weight prep v2: 64x64 LDS-tile transpose, coalesced both sides.
// Tile map: blk 0-47 wq/wk/wv -> qkvT, 48-63 wo -> woT,
//           64-127 fw1 [256][1024] -> fw1T, 128-191 fw2 [1024][256] -> fw2T.
// ---------------------------------------------------------------------------
__global__ __launch_bounds__(256) void prep_weights(
    const float* __restrict__ wq, const float* __restrict__ wk,
    const float* __restrict__ wv, const float* __restrict__ wo,
    const float* __restrict__ fw1, const float* __restrict__ fw2,
    unsigned short* __restrict__ qkvT, unsigned short* __restrict__ woT,
    unsigned short* __restrict__ fw1T, unsigned short* __restrict__ fw2T) {
  __shared__ float T[64][65];
  const int t = blockIdx.x;
  const float* src;
  unsigned short* dst;
  int R, Cn, tr, tc;
  if (t < 64) {  // 256x256 matrices, 16 tiles each
    int m = t >> 4, tt = t & 15;
    src = m == 0 ? wq : (m == 1 ? wk : (m == 2 ? wv : wo));
    dst = m < 3 ? qkvT + m * 65536 : woT;
    R = 256; Cn = 256; tr = tt >> 2; tc = tt & 3;
  } else if (t < 128) {  // fw1 [256][1024]
    int tt = t - 64;
    src = fw1; dst = fw1T; R = 256; Cn = 1024;
    tr = tt >> 4; tc = tt & 15;
  } else {               // fw2 [1024][256]
    int tt = t - 128;
    src = fw2; dst = fw2T; R = 1024; Cn = 256;
    tr = tt >> 2; tc = tt & 3;
  }
  const int r0 = threadIdx.x >> 4, c4 = threadIdx.x & 15;
#pragma unroll
  for (int it = 0; it < 4; ++it) {
    int row = it * 16 + r0;
    *(float4*)&T[row][c4 * 4] =
        *(const float4*)(src + (size_t)(tr * 64 + row) * Cn + tc * 64 + c4 * 4);
  }
  __syncthreads();
  const int c0 = threadIdx.x >> 2, seg = threadIdx.x & 3;
  unsigned short tmp[16];
#pragma unroll
  for (int j = 0; j < 16; ++j) tmp[j] = f2bf(T[seg * 16 + j][c0]);
  unsigned short* dp = dst + (size_t)(tc * 64 + c0) * R + tr * 64 + seg * 16;
  *(uint4*)dp = *(uint4*)&tmp[0];
  *(uint4*)(dp + 8) = *(uint4*)&tmp[8];
}

// ---------------------------------------------------------------------------
// bf16 MFMA GEMM, glds staging, BK=64, XOR-swizzled unpadded LDS [128][64].
// XCD-aware bijective blockIdx swizzle (all launches have nwg%8==0).
// OUT: 0 fp32->Cf; 1 bf16->C2; 2 both; 3 bf16 QKV split (col>>8 buffer).
// ---------------------------------------------------------------------------
template <int K, bool BIAS, bool RELU, bool RESID, int OUT>
__global__ __launch_bounds__(256) void gemm_mfma(
    const unsigned short* __restrict__ A, const unsigned short* __restrict__ Bt,
    const float* __restrict__ bias, const float* __restrict__ resid,
    float* __restrict__ Cf, unsigned short* __restrict__ C2, int N) {
  __shared__ unsigned short As[128 * 64];
  __shared__ unsigned short Bs[128 * 64];
  const int tid = threadIdx.x;
  const int nwg = gridDim.x * gridDim.y;
  const int bid0 = blockIdx.y * gridDim.x + blockIdx.x;
  const int swz = (bid0 & 7) * (nwg >> 3) + (bid0 >> 3);
  const int rowBase = (swz / gridDim.x) * 128;
  const int colBase = (swz % gridDim.x) * 128;
  const int wave = tid >> 6, lane = tid & 63;
  const int wm = wave >> 1, wn = wave & 1;
  const int quad = lane >> 4, l15 = lane & 15;
  const int s8 = (((lane & 7) ^ (lane >> 3)) << 3);  // swizzled global chunk
  const int rs0 = (wave << 5) + (lane >> 3);         // staged row base
  const int swzf = l15 & 7;

  floatx4 acc[4][4];
#pragma unroll
  for (int mt = 0; mt < 4; ++mt)
#pragma unroll
    for (int nt = 0; nt < 4; ++nt) acc[mt][nt] = (floatx4){0.f, 0.f, 0.f, 0.f};

  for (int k0 = 0; k0 < K; k0 += 64) {
#pragma unroll
    for (int i = 0; i < 4; ++i) {
      int r = rs0 + (i << 3);
      int lb = wave * 2048 + i * 512;
      glds16(A + (size_t)(rowBase + r) * K + k0 + s8, &As[lb]);
      glds16(Bt + (size_t)(colBase + r) * K + k0 + s8, &Bs[lb]);
    }
    __syncthreads();
#pragma unroll
    for (int kk = 0; kk < 2; ++kk) {
      short8 af[4], bfr[4];
#pragma unroll
      for (int mt = 0; mt < 4; ++mt)
        af[mt] = *(const short8*)&As[(wm * 64 + mt * 16 + l15) * 64 +
                                     ((((kk << 2) | quad) ^ swzf) << 3)];
#pragma unroll
      for (int nt = 0; nt < 4; ++nt)
        bfr[nt] = *(const short8*)&Bs[(wn * 64 + nt * 16 + l15) * 64 +
                                      ((((kk << 2) | quad) ^ swzf) << 3)];
#pragma unroll
      for (int mt = 0; mt < 4; ++mt)
#pragma unroll
        for (int nt = 0; nt < 4; ++nt)
          acc[mt][nt] = __builtin_amdgcn_mfma_f32_16x16x32_bf16(
              af[mt], bfr[nt], acc[mt][nt], 0, 0, 0);
    }
    __syncthreads();
  }

#pragma unroll
  for (int mt = 0; mt < 4; ++mt) {
#pragma unroll
    for (int nt = 0; nt < 4; ++nt) {
      int col = colBase + wn * 64 + nt * 16 + l15;
      float bz = BIAS ? bias[col] : 0.f;
#pragma unroll
      for (int i = 0; i < 4; ++i) {
        int row = rowBase + wm * 64 + mt * 16 + quad * 4 + i;
        float v = acc[mt][nt][i];
        if (BIAS) v += bz;
        if (RELU) v = fmaxf(v, 0.f);
        if (RESID) v += resid[(size_t)row * N + col];
        if (OUT == 0) {
          Cf[(size_t)row * N + col] = v;
        } else if (OUT == 1) {
          C2[(size_t)row * N + col] = f2bf(v);
        } else if (OUT == 2) {
          Cf[(size_t)row * N + col] = v;
          C2[(size_t)row * N + col] = f2bf(v);
        } else {  // QKV split
          C2[(size_t)(col >> 8) * 16777216 + (size_t)row * 256 + (col & 255)] =
              f2bf(v);
        }
      }
    }
  }
}

// ---------------------------------------------------------------------------
// DAG stage 0a: embed_init_w [25001][256] fp32 -> emb16 [25088][256] bf16
// ---------------------------------------------------------------------------
__global__ __launch_bounds__(256) void cvt_emb16(
    const float* __restrict__ emb, unsigned short* __restrict__ e16) {
  int gid = blockIdx.x * 256 + threadIdx.x;  // 802816 threads, 8 elems each
  int base = gid * 8;
  int row = base >> 8;
  uint4 o;
  if (row < 25001) {
    float4 a = *(const float4*)(emb + base);
    float4 b = *(const float4*)(emb + base + 4);
    o.x = pack2(a.x, a.y); o.y = pack2(a.z, a.w);
    o.z = pack2(b.x, b.y); o.w = pack2(b.z, b.w);
  } else {
    o = (uint4){0u, 0u, 0u, 0u};
  }
  *(uint4*)(e16 + base) = o;
}

// ---------------------------------------------------------------------------
// DAG stage 0b: w1 [512,256] -> Bt [512][256] bf16 (P | Q split).
// ---------------------------------------------------------------------------
__global__ __launch_bounds__(256) void prep_w1T_pq(
    const float* __restrict__ w1, unsigned short* __restrict__ Bt) {
  int gid = blockIdx.x * 256 + threadIdx.x;  // 131072
  int n = gid >> 8, k = gid & 255;
  float v = (n < 256) ? w1[k * 256 + n] : w1[(256 + k) * 256 + (n - 256)];
  Bt[gid] = f2bf(v);
}

// ---------------------------------------------------------------------------
// DAG fused score+softmax+gather: one block per code.
// ---------------------------------------------------------------------------
__global__ __launch_bounds__(256) void dag_fused(
    const int* __restrict__ leaves, const int* __restrict__ anc,
    const unsigned short* __restrict__ PQ, const float* __restrict__ b1,
    const float* __restrict__ w2, const float* __restrict__ b2,
    const float* __restrict__ masks, const unsigned short* __restrict__ emb16,
    float* __restrict__ dict) {
  const int c = blockIdx.x;
  const int t = threadIdx.x;
  const int a = t >> 5, l32 = t & 31;
  __shared__ float sv[8], mv[8];
  __shared__ int nv[8];

  // ---- score ----
  float b1c[8], w2c[8];
  *(float4*)&b1c[0] = *(const float4*)(b1 + l32 * 8);
  *(float4*)&b1c[4] = *(const float4*)(b1 + l32 * 8 + 4);
  *(float4*)&w2c[0] = *(const float4*)(w2 + l32 * 8);
  *(float4*)&w2c[4] = *(const float4*)(w2 + l32 * 8 + 4);
  const int idx = c * 8 + a;
  const int nl = leaves[idx], na = anc[idx];
  uint4 pv = *(const uint4*)(PQ + (size_t)nl * 512 + l32 * 8);
  uint4 qv = *(const uint4*)(PQ + (size_t)na * 512 + 256 + l32 * 8);
  const unsigned short* pu = (const unsigned short*)&pv;
  const unsigned short* qu = (const unsigned short*)&qv;
  float acc = 0.f;
#pragma unroll
  for (int j = 0; j < 8; ++j) {
    float h = bf2f(pu[j]) + bf2f(qu[j]) + b1c[j];
    acc += fmaxf(h, 0.f) * w2c[j];
  }
  acc += __shfl_xor(acc, 1, 32);
  acc += __shfl_xor(acc, 2, 32);
  acc += __shfl_xor(acc, 4, 32);
  acc += __shfl_xor(acc, 8, 32);
  acc += __shfl_xor(acc, 16, 32);
  if (l32 == 0) {
    float m = masks[idx];
    sv[a] = acc + b2[0] + (1.f - m) * VERY_NEG;
    mv[a] = m;
    nv[a] = na;
  }
  __syncthreads();

  // ---- softmax + masked ancestor gather (t = output column) ----
  float mx = -INFINITY;
#pragma unroll
  for (int aa = 0; aa < 8; ++aa) mx = fmaxf(mx, sv[aa]);
  float e[8], sum = 0.f;
#pragma unroll
  for (int aa = 0; aa < 8; ++aa) { e[aa] = __expf(sv[aa] - mx); sum += e[aa]; }
  float inv = 1.f / sum;
  float o = 0.f;
#pragma unroll
  for (int aa = 0; aa < 8; ++aa)
    o += e[aa] * inv * mv[aa] * bf2f(emb16[(size_t)nv[aa] * 256 + t]);
  dict[(size_t)(c + 1) * 256 + t] = o;
  if (c == 0) dict[t] = 0.f;
}

// ---------------------------------------------------------------------------
// Row gather -> fp32 AND bf16 (dual write; table read once).
// ---------------------------------------------------------------------------
__global__ __launch_bounds__(256) void gather_both(
    const int* __restrict__ ids, const float4* __restrict__ table,
    float4* __restrict__ outf, unsigned short* __restrict__ outb) {
  int gid = blockIdx.x * 256 + threadIdx.x;
  int row = gid >> 6;
  int c4 = gid & 63;
  float4 v = table[(size_t)ids[row] * 64 + c4];
  outf[gid] = v;
  uint2 o;
  o.x = pack2(v.x, v.y);
  o.y = pack2(v.z, v.w);
  *(uint2*)(outb + (size_t)gid * 4) = o;
}

// ---------------------------------------------------------------------------
// MFMA flash attention, v3: sum-via-ones-MFMA softmax, split-ks P buffer,
// swizzled LDS, 4 blocks/CU. (See round-3 notes.)
// ---------------------------------------------------------------------------
static __device__ __forceinline__ int vt_addr(int d, int col) {
  return d * 272 + ((((col) * 2) ^ (((d >> 3) & 3) << 4)) >> 1);
}
static __device__ __forceinline__ int ps_addr(int row, int col) {
  return row * 40 + ((((col) * 2) ^ (((row >> 2) & 3) << 4)) >> 1);
}

__global__ __launch_bounds__(256, 4) void attn_mfma(
    const unsigned short* __restrict__ q, const unsigned short* __restrict__ k,
    const unsigned short* __restrict__ v, const float* __restrict__ cm,
    unsigned short* __restrict__ ctx) {
  __shared__ unsigned short Vt[32 * 272];   // [d][seq], swizzled
  __shared__ unsigned short Ps[4][64 * 40]; // wave-private 64x32 P slab
  __shared__ float madd[256];
  const int b = blockIdx.x >> 3, h = blockIdx.x & 7;
  const int tid = threadIdx.x;
  const int wave = tid >> 6, lane = tid & 63;
  const int quad = lane >> 4, l15 = lane & 15;
  const size_t tokbase = (size_t)b * 256;
  const int hoff = h * 32;

  // V load + transpose (direct global -> scatter into swizzled Vt)
#pragma unroll
  for (int it = 0; it < 4; ++it) {
    int idx = tid + it * 256;
    int row = idx >> 2, c = idx & 3;
    uint4 w = *(const uint4*)(v + (tokbase + row) * 256 + hoff + c * 8);
    const unsigned short* wsp = (const unsigned short*)&w;
#pragma unroll
    for (int j = 0; j < 8; ++j) Vt[vt_addr(c * 8 + j, row)] = wsp[j];
  }
  madd[tid] = (1.f - cm[b * 256 + tid]) * VERY_NEG;
  __syncthreads();

  short8 qf[4];
#pragma unroll
  for (int mt = 0; mt < 4; ++mt) {
    size_t qrow = tokbase + wave * 64 + mt * 16 + l15;
    qf[mt] = *(const short8*)(q + qrow * 256 + hoff + quad * 8);
  }
  float madd_r[16];
#pragma unroll
  for (int nt = 0; nt < 16; ++nt) madd_r[nt] = madd[nt * 16 + l15];

  // constant ones-column B-fragment: B[k][0]=1, else 0.
  short8 vone;
#pragma unroll
  for (int j = 0; j < 8; ++j)
    ((unsigned short*)&vone)[j] = (l15 == 0) ? 0x3F80 : 0;

  floatx4 oa[4][2], oa_l[4];
#pragma unroll
  for (int mt = 0; mt < 4; ++mt) {
    oa_l[mt] = (floatx4){0.f, 0.f, 0.f, 0.f};
#pragma unroll
    for (int nd = 0; nd < 2; ++nd) oa[mt][nd] = (floatx4){0.f, 0.f, 0.f, 0.f};
  }

  const float scale = 0.17677669529663687f;  // 1/sqrt(32)
  unsigned short* Pw = &Ps[wave][0];

  for (int t = 0; t < 4; ++t) {
    // K fragments straight from global (L2-hit after first wave).
    short8 kf[4];
#pragma unroll
    for (int nt = 0; nt < 4; ++nt)
      kf[nt] = *(const short8*)(k + (tokbase + t * 64 + nt * 16 + l15) * 256 +
                                hoff + quad * 8);
    floatx4 sa[4][4];
#pragma unroll
    for (int mt = 0; mt < 4; ++mt)
#pragma unroll
      for (int nt = 0; nt < 4; ++nt) sa[mt][nt] = (floatx4){0.f, 0.f, 0.f, 0.f};
#pragma unroll
    for (int mt = 0; mt < 4; ++mt)
#pragma unroll
      for (int nt = 0; nt < 4; ++nt)
        sa[mt][nt] = __builtin_amdgcn_mfma_f32_16x16x32_bf16(
            qf[mt], kf[nt], sa[mt][nt], 0, 0, 0);

#pragma unroll
    for (int ks = 0; ks < 2; ++ks) {
      // exp + pack + write the 32-k slab (elementwise only).
#pragma unroll
      for (int mt = 0; mt < 4; ++mt)
#pragma unroll
        for (int n2 = 0; n2 < 2; ++n2) {
          int nt = ks * 2 + n2;
#pragma unroll
          for (int i = 0; i < 4; ++i) {
            float p = __expf(sa[mt][nt][i] * scale + madd_r[t * 4 + nt]);
            Pw[ps_addr(mt * 16 + quad * 4 + i, n2 * 16 + l15)] = f2bf(p);
          }
        }
      __asm__ __volatile__("s_waitcnt lgkmcnt(0)" ::: "memory");
      short8 vf[2];
#pragma unroll
      for (int nd = 0; nd < 2; ++nd)
        vf[nd] = *(const short8*)&Vt[vt_addr(nd * 16 + l15,
                                             t * 64 + ks * 32 + quad * 8)];
#pragma unroll
      for (int mt = 0; mt < 4; ++mt) {
        short8 pf = *(const short8*)&Pw[ps_addr(mt * 16 + l15, quad * 8)];
#pragma unroll
        for (int nd = 0; nd < 2; ++nd)
          oa[mt][nd] = __builtin_amdgcn_mfma_f32_16x16x32_bf16(
              pf, vf[nd], oa[mt][nd], 0, 0, 0);
        oa_l[mt] = __builtin_amdgcn_mfma_f32_16x16x32_bf16(
            pf, vone, oa_l[mt], 0, 0, 0);
      }
    }
  }

  // epilogue: broadcast row sums (held at l15==0 lanes), normalize, store.
  float inv[4][4];
#pragma unroll
  for (int mt = 0; mt < 4; ++mt)
#pragma unroll
    for (int i = 0; i < 4; ++i) {
      float l = __shfl(oa_l[mt][i], lane & 48, 64);
      inv[mt][i] = 1.f / l;
    }
#pragma unroll
  for (int mt = 0; mt < 4; ++mt)
#pragma unroll
    for (int nd = 0; nd < 2; ++nd)
#pragma unroll
      for (int i = 0; i < 4; ++i)
        Pw[ps_addr(mt * 16 + quad * 4 + i, nd * 16 + l15)] =
            f2bf(oa[mt][nd][i] * inv[mt][i]);
  __asm__ __volatile__("s_waitcnt lgkmcnt(0)" ::: "memory");
#pragma unroll
  for (int it = 0; it < 4; ++it) {
    int idx = it * 64 + lane;
    int row = idx >> 2, c = idx & 3;
    uint4 w = *(const uint4*)&Pw[ps_addr(row, c * 8)];
    *(uint4*)(ctx + (tokbase + wave * 64 + row) * 256 + hoff + c * 8) = w;
  }
}

// ---------------------------------------------------------------------------
// Attention pooling v3: 256 blocks (2 per batch, 128 cols each), 512 thr.
// Phase 1: scores with 2 threads/row (depth-32 chains), LDS combine,
// max/sum tree. Phase 2: weighted sum split into 16 si-groups x 32 col4
// (depth-16 chains), LDS combine. Full-GPU grid; x[b] L2-resident for the
// second col-half block.
// ---------------------------------------------------------------------------
__global__ __launch_bounds__(512) void pool_kernel(
    const float* __restrict__ x, const float* __restrict__ code_mask,
    const float* __restrict__ pw, const float* __restrict__ pb,
    float* __restrict__ out) {
  const int bx = blockIdx.x;        // 256 blocks
  const int b = bx >> 1;
  const int colBase = (bx & 1) * 128;
  const int t = threadIdx.x;        // 0..511
  __shared__ float part[512];
  __shared__ float ss[256];
  __shared__ float red[256];
  __shared__ float als[256];
  __shared__ float osum[16][32][4];
  const float* xb = x + (size_t)b * 65536;

  // phase 1: scores, 2 threads per row (128 elems each)
  {
    int row = t & 255, h2 = t >> 8;
    const float* xr = xb + (size_t)row * 256 + h2 * 128;
    const float* wr = pw + h2 * 128;
    float s = 0.f;
#pragma unroll 8
    for (int j = 0; j < 128; j += 4) {
      float4 xv = *(const float4*)(xr + j);
      float4 wv = *(const float4*)(wr + j);
      s += xv.x * wv.x + xv.y * wv.y + xv.z * wv.z + xv.w * wv.w;
    }
    part[t] = s;
  }
  __syncthreads();
  if (t < 256) {
    float s = part[t] + part[t + 256] + pb[0] +
              (1.f - code_mask[b * 256 + t]) * VERY_NEG;
    ss[t] = s; red[t] = s;
  }
  __syncthreads();
  for (int off = 128; off > 0; off >>= 1) {
    if (t < off) red[t] = fmaxf(red[t], red[t + off]);
    __syncthreads();
  }
  float m = red[0];
  __syncthreads();
  if (t < 256) {
    float e = __expf(ss[t] - m);
    als[t] = e; red[t] = e;
  }
  __syncthreads();
  for (int off = 128; off > 0; off >>= 1) {
    if (t < off) red[t] += red[t + off];
    __syncthreads();
  }
  float inv = 1.f / red[0];

  // phase 2: weighted sum, 16 si-groups x 32 col4-slots
  {
    int cg = t & 31, grp = t >> 5;
    int col = colBase + cg * 4;
    float4 acc = {0.f, 0.f, 0.f, 0.f};
#pragma unroll 4
    for (int si = grp * 16; si < grp * 16 + 16; ++si) {
      float a = als[si];
      float4 xv = *(const float4*)(xb + (size_t)si * 256 + col);
      acc.x += a * xv.x; acc.y += a * xv.y;
      acc.z += a * xv.z; acc.w += a * xv.w;
    }
    *(float4*)&osum[grp][cg][0] = acc;
  }
  __syncthreads();
  if (t < 128) {
    int cg = t >> 2, comp = t & 3;
    float o = 0.f;
#pragma unroll
    for (int g = 0; g < 16; ++g) o += osum[g][cg][comp];
    out[b * 256 + colBase + cg * 4 + comp] = o * inv;
  }
}

// ---------------------------------------------------------------------------
extern "C" void kernel_launch(void* const* d_in, const int* in_sizes, int n_in,
                              void* d_out, int out_size, void* d_ws,
                              size_t ws_size, hipStream_t stream) {
  const int* input_ids = (const int*)d_in[0];
  const float* code_mask = (const float*)d_in[1];
  const int* dx_leaves = (const int*)d_in[2];
  const int* dx_anc = (const int*)d_in[3];
  const float* dx_masks = (const float*)d_in[4];
  const float* embed_init_w = (const float*)d_in[5];
  const float* embed_inputs_w = (const float*)d_in[6];
  const float* attn_w1 = (const float*)d_in[7];
  const float* attn_b1 = (const float*)d_in[8];
  const float* attn_w2 = (const float*)d_in[9];
  const float* attn_b2 = (const float*)d_in[10];
  const float* pool_w = (const float*)d_in[11];
  const float* pool_b = (const float*)d_in[12];

  float* out = (float*)d_out;
  float* ws = (float*)d_ws;

  // workspace layout (floats)
  float* dict = ws;                      // 5,120,256
  float* xbuf = dict + 5120256;          // 8,388,608
  float* qb   = xbuf + 8388608;          // 8,388,608
  float* kb   = qb + 8388608;            // 8,388,608
  float* vb   = kb + 8388608;            // 8,388,608
  float* ctxb = vb + 8388608;            // 8,388,608
  float* wend = ctxb + 8388608;          // weight area (393,216 floats)

  // DAG-phase aliases over regions dead until the encoder phase:
  unsigned short* emb16  = (unsigned short*)xbuf;             // 6,422,528 ush
  unsigned short* pq16   = (unsigned short*)(xbuf + 3211264); // 12,845,056 ush (spills into qb)
  unsigned short* w1T_pq = (unsigned short*)kb;               // 131,072 ush

  // encoder-phase aliases:
  unsigned short* xb16  = (unsigned short*)ctxb;  // bf16(x) pre-QKV, later ctx
  unsigned short* qkv16 = (unsigned short*)qb;    // q/k/v bf16, 16777216 stride
  unsigned short* xq16  = (unsigned short*)qb;    // bf16(x) post-WO (q dead)
  unsigned short* hid16 = (unsigned short*)kb;    // FFN hidden [32768][1024] (k+v)
  // bf16 weights:
  unsigned short* qkvT = (unsigned short*)wend;   // 196,608
  unsigned short* woT  = qkvT + 196608;           // 65,536
  unsigned short* fw1T = woT + 65536;             // 262,144
  unsigned short* fw2T = fw1T + 262144;           // 262,144

  // 1) DAG embedding -> dict_matrix (factored PQ path, fused score+finalize).
  cvt_emb16<<<3136, 256, 0, stream>>>(embed_init_w, emb16);
  prep_w1T_pq<<<512, 256, 0, stream>>>(attn_w1, w1T_pq);
  gemm_mfma<256, false, false, false, 1><<<dim3(4, 196), 256, 0, stream>>>(
      emb16, w1T_pq, nullptr, nullptr, nullptr, pq16, 512);
  dag_fused<<<Cc, 256, 0, stream>>>(dx_leaves, dx_anc, pq16, attn_b1, attn_w2,
                                    attn_b2, dx_masks, emb16, dict);

  auto run_encoder = [&](const float* wq, const float* wk, const float* wv,
                         const float* wo, const float* fw1, const float* fb1,
                         const float* fw2, const float* fb2, float* final_out) {
    prep_weights<<<192, 256, 0, stream>>>(wq, wk, wv, wo, fw1, fw2, qkvT,
                                          woT, fw1T, fw2T);
    // fused QKV: N=768, bf16 split-output into q/k/v buffers
    gemm_mfma<256, false, false, false, 3><<<dim3(6, 256), 256, 0, stream>>>(
        xb16, qkvT, nullptr, nullptr, nullptr, qkv16, 256);
    // MFMA flash attention -> bf16 ctx (into xb16 region; dead post-QKV)
    attn_mfma<<<Bc * NHc, 256, 0, stream>>>(qkv16, qkv16 + 16777216,
                                            qkv16 + 33554432, code_mask, xb16);
    // x += ctx @ wo  (fp32 resid out to xbuf, bf16 copy to xq16)
    gemm_mfma<256, false, false, true, 2><<<dim3(2, 256), 256, 0, stream>>>(
        xb16, woT, nullptr, xbuf, xbuf, xq16, 256);
    // FFN (split pair: best-measured config; hid16 is L3-resident)
    gemm_mfma<256, true, true, false, 1><<<dim3(8, 256), 256, 0, stream>>>(
        xq16, fw1T, fb1, nullptr, nullptr, hid16, 1024);
    gemm_mfma<1024, true, false, true, 0><<<dim3(2, 256), 256, 0, stream>>>(
        hid16, fw2T, fb2, xbuf, final_out, nullptr, 256);
  };

  // 2) visit stream
  gather_both<<<8192, 256, 0, stream>>>(input_ids,
                                        (const float4*)embed_inputs_w,
                                        (float4*)xbuf, xb16);
  run_encoder((const float*)d_in[13], (const float*)d_in[14],
              (const float*)d_in[15], (const float*)d_in[16],
              (const float*)d_in[17], (const float*)d_in[18],
              (const float*)d_in[19], (const float*)d_in[20], out);

  // 3) dag stream
  gather_both<<<8192, 256, 0, stream>>>(input_ids, (const float4*)dict,
                                        (float4*)xbuf, xb16);
  run_encoder((const float*)d_in[21], (const float*)d_in[22],
              (const float*)d_in[23], (const float*)d_in[24],
              (const float*)d_in[25], (const float*)d_in[26],
              (const float*)d_in[27], (const float*)d_in[28], xbuf);

  pool_kernel<<<256, 512, 0, stream>>>(xbuf, code_mask, pool_w, pool_b,
                                       out + 8388608);
}

// Round 10
// 529.056 us; speedup vs baseline: 1.0723x; 1.0111x over previous
//
#include <hip/hip_runtime.h>
#include <hip/hip_bf16.h>
#include <math.h>

#define VERY_NEG (-1e30f)

// B=128, S=256, H=256, C=20000, NODES=25000, A=8, NH=8, d=32, FF=1024
constexpr int Bc = 128, Sc = 256, Hc = 256, Cc = 20000, Ac = 8, NHc = 8, DHc = 32, FFc = 1024;
constexpr int Mc = Bc * Sc;  // 32768 rows
constexpr int Rc = Cc * Ac;  // 160000 dag rows

typedef __attribute__((ext_vector_type(8))) short short8;
typedef __attribute__((ext_vector_type(4))) float floatx4;

static __device__ __forceinline__ unsigned short f2bf(float f) {
  union { float f; unsigned u; } v; v.f = f;
  unsigned r = v.u + 0x7FFF + ((v.u >> 16) & 1);   // RNE
  return (unsigned short)(r >> 16);
}
static __device__ __forceinline__ unsigned pack2(float lo, float hi) {
  return (unsigned)f2bf(lo) | ((unsigned)f2bf(hi) << 16);
}
static __device__ __forceinline__ float bf2f(unsigned short u) {
  union { unsigned u; float f; } v; v.u = ((unsigned)u) << 16; return v.f;
}

// async global->LDS, 16B per lane; lane i lands at base + i*16.
static __device__ __forceinline__ void glds16(const unsigned short* g,
                                              unsigned short* l) {
  __builtin_amdgcn_global_load_lds(
      (const __attribute__((address_space(1))) void*)g,
      (__attribute__((address_space(3))) void*)l, 16, 0, 0);
}

// ---------------------------------------------------------------------------
// Per-layer weight prep v2: 64x64 LDS-tile transpose, coalesced both sides.
// Tile map: blk 0-47 wq/wk/wv -> qkvT, 48-63 wo -> woT,
//           64-127 fw1 [256][1024] -> fw1T, 128-191 fw2 [1024][256] -> fw2T.
// ---------------------------------------------------------------------------
__global__ __launch_bounds__(256) void prep_weights(
    const float* __restrict__ wq, const float* __restrict__ wk,
    const float* __restrict__ wv, const float* __restrict__ wo,
    const float* __restrict__ fw1, const float* __restrict__ fw2,
    unsigned short* __restrict__ qkvT, unsigned short* __restrict__ woT,
    unsigned short* __restrict__ fw1T, unsigned short* __restrict__ fw2T) {
  __shared__ float T[64][65];
  const int t = blockIdx.x;
  const float* src;
  unsigned short* dst;
  int R, Cn, tr, tc;
  if (t < 64) {  // 256x256 matrices, 16 tiles each
    int m = t >> 4, tt = t & 15;
    src = m == 0 ? wq : (m == 1 ? wk : (m == 2 ? wv : wo));
    dst = m < 3 ? qkvT + m * 65536 : woT;
    R = 256; Cn = 256; tr = tt >> 2; tc = tt & 3;
  } else if (t < 128) {  // fw1 [256][1024]
    int tt = t - 64;
    src = fw1; dst = fw1T; R = 256; Cn = 1024;
    tr = tt >> 4; tc = tt & 15;
  } else {               // fw2 [1024][256]
    int tt = t - 128;
    src = fw2; dst = fw2T; R = 1024; Cn = 256;
    tr = tt >> 2; tc = tt & 3;
  }
  const int r0 = threadIdx.x >> 4, c4 = threadIdx.x & 15;
#pragma unroll
  for (int it = 0; it < 4; ++it) {
    int row = it * 16 + r0;
    *(float4*)&T[row][c4 * 4] =
        *(const float4*)(src + (size_t)(tr * 64 + row) * Cn + tc * 64 + c4 * 4);
  }
  __syncthreads();
  const int c0 = threadIdx.x >> 2, seg = threadIdx.x & 3;
  unsigned short tmp[16];
#pragma unroll
  for (int j = 0; j < 16; ++j) tmp[j] = f2bf(T[seg * 16 + j][c0]);
  unsigned short* dp = dst + (size_t)(tc * 64 + c0) * R + tr * 64 + seg * 16;
  *(uint4*)dp = *(uint4*)&tmp[0];
  *(uint4*)(dp + 8) = *(uint4*)&tmp[8];
}

// ---------------------------------------------------------------------------
// bf16 MFMA GEMM, glds staging, BK=64, XOR-swizzled unpadded LDS [128][64].
// XCD-aware bijective blockIdx swizzle (all launches have nwg%8==0).
// OUT: 0 fp32->Cf; 1 bf16->C2; 2 both;
//      3 bf16 QKV split, HEAD-MAJOR [which][h][tok][32] (attn reads coalesce).
// ---------------------------------------------------------------------------
template <int K, bool BIAS, bool RELU, bool RESID, int OUT>
__global__ __launch_bounds__(256) void gemm_mfma(
    const unsigned short* __restrict__ A, const unsigned short* __restrict__ Bt,
    const float* __restrict__ bias, const float* __restrict__ resid,
    float* __restrict__ Cf, unsigned short* __restrict__ C2, int N) {
  __shared__ unsigned short As[128 * 64];
  __shared__ unsigned short Bs[128 * 64];
  const int tid = threadIdx.x;
  const int nwg = gridDim.x * gridDim.y;
  const int bid0 = blockIdx.y * gridDim.x + blockIdx.x;
  const int swz = (bid0 & 7) * (nwg >> 3) + (bid0 >> 3);
  const int rowBase = (swz / gridDim.x) * 128;
  const int colBase = (swz % gridDim.x) * 128;
  const int wave = tid >> 6, lane = tid & 63;
  const int wm = wave >> 1, wn = wave & 1;
  const int quad = lane >> 4, l15 = lane & 15;
  const int s8 = (((lane & 7) ^ (lane >> 3)) << 3);  // swizzled global chunk
  const int rs0 = (wave << 5) + (lane >> 3);         // staged row base
  const int swzf = l15 & 7;

  floatx4 acc[4][4];
#pragma unroll
  for (int mt = 0; mt < 4; ++mt)
#pragma unroll
    for (int nt = 0; nt < 4; ++nt) acc[mt][nt] = (floatx4){0.f, 0.f, 0.f, 0.f};

  for (int k0 = 0; k0 < K; k0 += 64) {
#pragma unroll
    for (int i = 0; i < 4; ++i) {
      int r = rs0 + (i << 3);
      int lb = wave * 2048 + i * 512;
      glds16(A + (size_t)(rowBase + r) * K + k0 + s8, &As[lb]);
      glds16(Bt + (size_t)(colBase + r) * K + k0 + s8, &Bs[lb]);
    }
    __syncthreads();
#pragma unroll
    for (int kk = 0; kk < 2; ++kk) {
      short8 af[4], bfr[4];
#pragma unroll
      for (int mt = 0; mt < 4; ++mt)
        af[mt] = *(const short8*)&As[(wm * 64 + mt * 16 + l15) * 64 +
                                     ((((kk << 2) | quad) ^ swzf) << 3)];
#pragma unroll
      for (int nt = 0; nt < 4; ++nt)
        bfr[nt] = *(const short8*)&Bs[(wn * 64 + nt * 16 + l15) * 64 +
                                      ((((kk << 2) | quad) ^ swzf) << 3)];
#pragma unroll
      for (int mt = 0; mt < 4; ++mt)
#pragma unroll
        for (int nt = 0; nt < 4; ++nt)
          acc[mt][nt] = __builtin_amdgcn_mfma_f32_16x16x32_bf16(
              af[mt], bfr[nt], acc[mt][nt], 0, 0, 0);
    }
    __syncthreads();
  }

#pragma unroll
  for (int mt = 0; mt < 4; ++mt) {
#pragma unroll
    for (int nt = 0; nt < 4; ++nt) {
      int col = colBase + wn * 64 + nt * 16 + l15;
      float bz = BIAS ? bias[col] : 0.f;
#pragma unroll
      for (int i = 0; i < 4; ++i) {
        int row = rowBase + wm * 64 + mt * 16 + quad * 4 + i;
        float v = acc[mt][nt][i];
        if (BIAS) v += bz;
        if (RELU) v = fmaxf(v, 0.f);
        if (RESID) v += resid[(size_t)row * N + col];
        if (OUT == 0) {
          Cf[(size_t)row * N + col] = v;
        } else if (OUT == 1) {
          C2[(size_t)row * N + col] = f2bf(v);
        } else if (OUT == 2) {
          Cf[(size_t)row * N + col] = v;
          C2[(size_t)row * N + col] = f2bf(v);
        } else {  // QKV split, head-major [which][h][tok][32]
          C2[(size_t)(col >> 8) * 16777216 +
             (size_t)((col >> 5) & 7) * 1048576 + (size_t)row * 32 +
             (col & 31)] = f2bf(v);
        }
      }
    }
  }
}

// ---------------------------------------------------------------------------
// DAG stage 0a: embed_init_w [25001][256] fp32 -> emb16 [25088][256] bf16
// ---------------------------------------------------------------------------
__global__ __launch_bounds__(256) void cvt_emb16(
    const float* __restrict__ emb, unsigned short* __restrict__ e16) {
  int gid = blockIdx.x * 256 + threadIdx.x;  // 802816 threads, 8 elems each
  int base = gid * 8;
  int row = base >> 8;
  uint4 o;
  if (row < 25001) {
    float4 a = *(const float4*)(emb + base);
    float4 b = *(const float4*)(emb + base + 4);
    o.x = pack2(a.x, a.y); o.y = pack2(a.z, a.w);
    o.z = pack2(b.x, b.y); o.w = pack2(b.z, b.w);
  } else {
    o = (uint4){0u, 0u, 0u, 0u};
  }
  *(uint4*)(e16 + base) = o;
}

// ---------------------------------------------------------------------------
// DAG stage 0b: w1 [512,256] -> Bt [512][256] bf16 (P | Q split).
// ---------------------------------------------------------------------------
__global__ __launch_bounds__(256) void prep_w1T_pq(
    const float* __restrict__ w1, unsigned short* __restrict__ Bt) {
  int gid = blockIdx.x * 256 + threadIdx.x;  // 131072
  int n = gid >> 8, k = gid & 255;
  float v = (n < 256) ? w1[k * 256 + n] : w1[(256 + k) * 256 + (n - 256)];
  Bt[gid] = f2bf(v);
}

// ---------------------------------------------------------------------------
// DAG fused score+softmax+gather: one block per code.
// ---------------------------------------------------------------------------
__global__ __launch_bounds__(256) void dag_fused(
    const int* __restrict__ leaves, const int* __restrict__ anc,
    const unsigned short* __restrict__ PQ, const float* __restrict__ b1,
    const float* __restrict__ w2, const float* __restrict__ b2,
    const float* __restrict__ masks, const unsigned short* __restrict__ emb16,
    float* __restrict__ dict) {
  const int c = blockIdx.x;
  const int t = threadIdx.x;
  const int a = t >> 5, l32 = t & 31;
  __shared__ float sv[8], mv[8];
  __shared__ int nv[8];

  // ---- score ----
  float b1c[8], w2c[8];
  *(float4*)&b1c[0] = *(const float4*)(b1 + l32 * 8);
  *(float4*)&b1c[4] = *(const float4*)(b1 + l32 * 8 + 4);
  *(float4*)&w2c[0] = *(const float4*)(w2 + l32 * 8);
  *(float4*)&w2c[4] = *(const float4*)(w2 + l32 * 8 + 4);
  const int idx = c * 8 + a;
  const int nl = leaves[idx], na = anc[idx];
  uint4 pv = *(const uint4*)(PQ + (size_t)nl * 512 + l32 * 8);
  uint4 qv = *(const uint4*)(PQ + (size_t)na * 512 + 256 + l32 * 8);
  const unsigned short* pu = (const unsigned short*)&pv;
  const unsigned short* qu = (const unsigned short*)&qv;
  float acc = 0.f;
#pragma unroll
  for (int j = 0; j < 8; ++j) {
    float h = bf2f(pu[j]) + bf2f(qu[j]) + b1c[j];
    acc += fmaxf(h, 0.f) * w2c[j];
  }
  acc += __shfl_xor(acc, 1, 32);
  acc += __shfl_xor(acc, 2, 32);
  acc += __shfl_xor(acc, 4, 32);
  acc += __shfl_xor(acc, 8, 32);
  acc += __shfl_xor(acc, 16, 32);
  if (l32 == 0) {
    float m = masks[idx];
    sv[a] = acc + b2[0] + (1.f - m) * VERY_NEG;
    mv[a] = m;
    nv[a] = na;
  }
  __syncthreads();

  // ---- softmax + masked ancestor gather (t = output column) ----
  float mx = -INFINITY;
#pragma unroll
  for (int aa = 0; aa < 8; ++aa) mx = fmaxf(mx, sv[aa]);
  float e[8], sum = 0.f;
#pragma unroll
  for (int aa = 0; aa < 8; ++aa) { e[aa] = __expf(sv[aa] - mx); sum += e[aa]; }
  float inv = 1.f / sum;
  float o = 0.f;
#pragma unroll
  for (int aa = 0; aa < 8; ++aa)
    o += e[aa] * inv * mv[aa] * bf2f(emb16[(size_t)nv[aa] * 256 + t]);
  dict[(size_t)(c + 1) * 256 + t] = o;
  if (c == 0) dict[t] = 0.f;
}

// ---------------------------------------------------------------------------
// Row gather -> fp32 AND bf16 (dual write; table read once).
// ---------------------------------------------------------------------------
__global__ __launch_bounds__(256) void gather_both(
    const int* __restrict__ ids, const float4* __restrict__ table,
    float4* __restrict__ outf, unsigned short* __restrict__ outb) {
  int gid = blockIdx.x * 256 + threadIdx.x;
  int row = gid >> 6;
  int c4 = gid & 63;
  float4 v = table[(size_t)ids[row] * 64 + c4];
  outf[gid] = v;
  uint2 o;
  o.x = pack2(v.x, v.y);
  o.y = pack2(v.z, v.w);
  *(uint2*)(outb + (size_t)gid * 4) = o;
}

// ---------------------------------------------------------------------------
// MFMA flash attention, v4: head-major QKV input [h][tok][32] -> all global
// fragment loads are wave-contiguous (16 tokens x 64B = 1KB/instr vs 64
// scattered 512B-strided lines in v3). ctx output stays token-major.
// Sum-via-ones-MFMA softmax, split-ks P buffer, swizzled LDS, 4 blocks/CU.
// ---------------------------------------------------------------------------
static __device__ __forceinline__ int vt_addr(int d, int col) {
  return d * 272 + ((((col) * 2) ^ (((d >> 3) & 3) << 4)) >> 1);
}
static __device__ __forceinline__ int ps_addr(int row, int col) {
  return row * 40 + ((((col) * 2) ^ (((row >> 2) & 3) << 4)) >> 1);
}

__global__ __launch_bounds__(256, 4) void attn_mfma(
    const unsigned short* __restrict__ q, const unsigned short* __restrict__ k,
    const unsigned short* __restrict__ v, const float* __restrict__ cm,
    unsigned short* __restrict__ ctx) {
  __shared__ unsigned short Vt[32 * 272];   // [d][seq], swizzled
  __shared__ unsigned short Ps[4][64 * 40]; // wave-private 64x32 P slab
  __shared__ float madd[256];
  const int b = blockIdx.x >> 3, h = blockIdx.x & 7;
  const int tid = threadIdx.x;
  const int wave = tid >> 6, lane = tid & 63;
  const int quad = lane >> 4, l15 = lane & 15;
  const size_t tokbase = (size_t)b * 256;
  const int hoff = h * 32;
  // head-major bases: [h][tok][32]
  const unsigned short* qh = q + (size_t)h * 1048576 + tokbase * 32;
  const unsigned short* kh = k + (size_t)h * 1048576 + tokbase * 32;
  const unsigned short* vh = v + (size_t)h * 1048576 + tokbase * 32;

  // V load (fully contiguous 64KB) + transpose into swizzled Vt
#pragma unroll
  for (int it = 0; it < 4; ++it) {
    int idx = tid + it * 256;
    int row = idx >> 2, c = idx & 3;
    uint4 w = *(const uint4*)(vh + (size_t)idx * 8);
    const unsigned short* wsp = (const unsigned short*)&w;
#pragma unroll
    for (int j = 0; j < 8; ++j) Vt[vt_addr(c * 8 + j, row)] = wsp[j];
  }
  madd[tid] = (1.f - cm[b * 256 + tid]) * VERY_NEG;
  __syncthreads();

  short8 qf[4];
#pragma unroll
  for (int mt = 0; mt < 4; ++mt)
    qf[mt] = *(const short8*)(qh + (size_t)(wave * 64 + mt * 16 + l15) * 32 +
                              quad * 8);
  float madd_r[16];
#pragma unroll
  for (int nt = 0; nt < 16; ++nt) madd_r[nt] = madd[nt * 16 + l15];

  // constant ones-column B-fragment: B[k][0]=1, else 0.
  short8 vone;
#pragma unroll
  for (int j = 0; j < 8; ++j)
    ((unsigned short*)&vone)[j] = (l15 == 0) ? 0x3F80 : 0;

  floatx4 oa[4][2], oa_l[4];
#pragma unroll
  for (int mt = 0; mt < 4; ++mt) {
    oa_l[mt] = (floatx4){0.f, 0.f, 0.f, 0.f};
#pragma unroll
    for (int nd = 0; nd < 2; ++nd) oa[mt][nd] = (floatx4){0.f, 0.f, 0.f, 0.f};
  }

  const float scale = 0.17677669529663687f;  // 1/sqrt(32)
  unsigned short* Pw = &Ps[wave][0];

  for (int t = 0; t < 4; ++t) {
    // K fragments: contiguous head-major reads (L2-hit after first wave).
    short8 kf[4];
#pragma unroll
    for (int nt = 0; nt < 4; ++nt)
      kf[nt] = *(const short8*)(kh + (size_t)(t * 64 + nt * 16 + l15) * 32 +
                                quad * 8);
    floatx4 sa[4][4];
#pragma unroll
    for (int mt = 0; mt < 4; ++mt)
#pragma unroll
      for (int nt = 0; nt < 4; ++nt) sa[mt][nt] = (floatx4){0.f, 0.f, 0.f, 0.f};
#pragma unroll
    for (int mt = 0; mt < 4; ++mt)
#pragma unroll
      for (int nt = 0; nt < 4; ++nt)
        sa[mt][nt] = __builtin_amdgcn_mfma_f32_16x16x32_bf16(
            qf[mt], kf[nt], sa[mt][nt], 0, 0, 0);

#pragma unroll
    for (int ks = 0; ks < 2; ++ks) {
      // exp + pack + write the 32-k slab (elementwise only).
#pragma unroll
      for (int mt = 0; mt < 4; ++mt)
#pragma unroll
        for (int n2 = 0; n2 < 2; ++n2) {
          int nt = ks * 2 + n2;
#pragma unroll
          for (int i = 0; i < 4; ++i) {
            float p = __expf(sa[mt][nt][i] * scale + madd_r[t * 4 + nt]);
            Pw[ps_addr(mt * 16 + quad * 4 + i, n2 * 16 + l15)] = f2bf(p);
          }
        }
      __asm__ __volatile__("s_waitcnt lgkmcnt(0)" ::: "memory");
      short8 vf[2];
#pragma unroll
      for (int nd = 0; nd < 2; ++nd)
        vf[nd] = *(const short8*)&Vt[vt_addr(nd * 16 + l15,
                                             t * 64 + ks * 32 + quad * 8)];
#pragma unroll
      for (int mt = 0; mt < 4; ++mt) {
        short8 pf = *(const short8*)&Pw[ps_addr(mt * 16 + l15, quad * 8)];
#pragma unroll
        for (int nd = 0; nd < 2; ++nd)
          oa[mt][nd] = __builtin_amdgcn_mfma_f32_16x16x32_bf16(
              pf, vf[nd], oa[mt][nd], 0, 0, 0);
        oa_l[mt] = __builtin_amdgcn_mfma_f32_16x16x32_bf16(
            pf, vone, oa_l[mt], 0, 0, 0);
      }
    }
  }

  // epilogue: broadcast row sums (held at l15==0 lanes), normalize, store.
  float inv[4][4];
#pragma unroll
  for (int mt = 0; mt < 4; ++mt)
#pragma unroll
    for (int i = 0; i < 4; ++i) {
      float l = __shfl(oa_l[mt][i], lane & 48, 64);
      inv[mt][i] = 1.f / l;
    }
#pragma unroll
  for (int mt = 0; mt < 4; ++mt)
#pragma unroll
    for (int nd = 0; nd < 2; ++nd)
#pragma unroll
      for (int i = 0; i < 4; ++i)
        Pw[ps_addr(mt * 16 + quad * 4 + i, nd * 16 + l15)] =
            f2bf(oa[mt][nd][i] * inv[mt][i]);
  __asm__ __volatile__("s_waitcnt lgkmcnt(0)" ::: "memory");
#pragma unroll
  for (int it = 0; it < 4; ++it) {
    int idx = it * 64 + lane;
    int row = idx >> 2, c = idx & 3;
    uint4 w = *(const uint4*)&Pw[ps_addr(row, c * 8)];
    *(uint4*)(ctx + (tokbase + wave * 64 + row) * 256 + hoff + c * 8) = w;
  }
}

// ---------------------------------------------------------------------------
// Attention pooling v3: 256 blocks (2 per batch, 128 cols each), 512 thr.
// ---------------------------------------------------------------------------
__global__ __launch_bounds__(512) void pool_kernel(
    const float* __restrict__ x, const float* __restrict__ code_mask,
    const float* __restrict__ pw, const float* __restrict__ pb,
    float* __restrict__ out) {
  const int bx = blockIdx.x;        // 256 blocks
  const int b = bx >> 1;
  const int colBase = (bx & 1) * 128;
  const int t = threadIdx.x;        // 0..511
  __shared__ float part[512];
  __shared__ float ss[256];
  __shared__ float red[256];
  __shared__ float als[256];
  __shared__ float osum[16][32][4];
  const float* xb = x + (size_t)b * 65536;

  // phase 1: scores, 2 threads per row (128 elems each)
  {
    int row = t & 255, h2 = t >> 8;
    const float* xr = xb + (size_t)row * 256 + h2 * 128;
    const float* wr = pw + h2 * 128;
    float s = 0.f;
#pragma unroll 8
    for (int j = 0; j < 128; j += 4) {
      float4 xv = *(const float4*)(xr + j);
      float4 wv = *(const float4*)(wr + j);
      s += xv.x * wv.x + xv.y * wv.y + xv.z * wv.z + xv.w * wv.w;
    }
    part[t] = s;
  }
  __syncthreads();
  if (t < 256) {
    float s = part[t] + part[t + 256] + pb[0] +
              (1.f - code_mask[b * 256 + t]) * VERY_NEG;
    ss[t] = s; red[t] = s;
  }
  __syncthreads();
  for (int off = 128; off > 0; off >>= 1) {
    if (t < off) red[t] = fmaxf(red[t], red[t + off]);
    __syncthreads();
  }
  float m = red[0];
  __syncthreads();
  if (t < 256) {
    float e = __expf(ss[t] - m);
    als[t] = e; red[t] = e;
  }
  __syncthreads();
  for (int off = 128; off > 0; off >>= 1) {
    if (t < off) red[t] += red[t + off];
    __syncthreads();
  }
  float inv = 1.f / red[0];

  // phase 2: weighted sum, 16 si-groups x 32 col4-slots
  {
    int cg = t & 31, grp = t >> 5;
    int col = colBase + cg * 4;
    float4 acc = {0.f, 0.f, 0.f, 0.f};
#pragma unroll 4
    for (int si = grp * 16; si < grp * 16 + 16; ++si) {
      float a = als[si];
      float4 xv = *(const float4*)(xb + (size_t)si * 256 + col);
      acc.x += a * xv.x; acc.y += a * xv.y;
      acc.z += a * xv.z; acc.w += a * xv.w;
    }
    *(float4*)&osum[grp][cg][0] = acc;
  }
  __syncthreads();
  if (t < 128) {
    int cg = t >> 2, comp = t & 3;
    float o = 0.f;
#pragma unroll
    for (int g = 0; g < 16; ++g) o += osum[g][cg][comp];
    out[b * 256 + colBase + cg * 4 + comp] = o * inv;
  }
}

// ---------------------------------------------------------------------------
extern "C" void kernel_launch(void* const* d_in, const int* in_sizes, int n_in,
                              void* d_out, int out_size, void* d_ws,
                              size_t ws_size, hipStream_t stream) {
  const int* input_ids = (const int*)d_in[0];
  const float* code_mask = (const float*)d_in[1];
  const int* dx_leaves = (const int*)d_in[2];
  const int* dx_anc = (const int*)d_in[3];
  const float* dx_masks = (const float*)d_in[4];
  const float* embed_init_w = (const float*)d_in[5];
  const float* embed_inputs_w = (const float*)d_in[6];
  const float* attn_w1 = (const float*)d_in[7];
  const float* attn_b1 = (const float*)d_in[8];
  const float* attn_w2 = (const float*)d_in[9];
  const float* attn_b2 = (const float*)d_in[10];
  const float* pool_w = (const float*)d_in[11];
  const float* pool_b = (const float*)d_in[12];

  float* out = (float*)d_out;
  float* ws = (float*)d_ws;

  // workspace layout (floats)
  float* dict = ws;                      // 5,120,256
  float* xbuf = dict + 5120256;          // 8,388,608
  float* qb   = xbuf + 8388608;          // 8,388,608
  float* kb   = qb + 8388608;            // 8,388,608
  float* vb   = kb + 8388608;            // 8,388,608
  float* ctxb = vb + 8388608;            // 8,388,608
  float* wend = ctxb + 8388608;          // weight area (393,216 floats)

  // DAG-phase aliases over regions dead until the encoder phase:
  unsigned short* emb16  = (unsigned short*)xbuf;             // 6,422,528 ush
  unsigned short* pq16   = (unsigned short*)(xbuf + 3211264); // 12,845,056 ush (spills into qb)
  unsigned short* w1T_pq = (unsigned short*)kb;               // 131,072 ush

  // encoder-phase aliases:
  unsigned short* xb16  = (unsigned short*)ctxb;  // bf16(x) pre-QKV, later ctx
  unsigned short* qkv16 = (unsigned short*)qb;    // q/k/v bf16, head-major
  unsigned short* xq16  = (unsigned short*)qb;    // bf16(x) post-WO (q dead)
  unsigned short* hid16 = (unsigned short*)kb;    // FFN hidden [32768][1024] (k+v)
  // bf16 weights:
  unsigned short* qkvT = (unsigned short*)wend;   // 196,608
  unsigned short* woT  = qkvT + 196608;           // 65,536
  unsigned short* fw1T = woT + 65536;             // 262,144
  unsigned short* fw2T = fw1T + 262144;           // 262,144

  // 1) DAG embedding -> dict_matrix (factored PQ path, fused score+finalize).
  cvt_emb16<<<3136, 256, 0, stream>>>(embed_init_w, emb16);
  prep_w1T_pq<<<512, 256, 0, stream>>>(attn_w1, w1T_pq);
  gemm_mfma<256, false, false, false, 1><<<dim3(4, 196), 256, 0, stream>>>(
      emb16, w1T_pq, nullptr, nullptr, nullptr, pq16, 512);
  dag_fused<<<Cc, 256, 0, stream>>>(dx_leaves, dx_anc, pq16, attn_b1, attn_w2,
                                    attn_b2, dx_masks, emb16, dict);

  auto run_encoder = [&](const float* wq, const float* wk, const float* wv,
                         const float* wo, const float* fw1, const float* fb1,
                         const float* fw2, const float* fb2, float* final_out) {
    prep_weights<<<192, 256, 0, stream>>>(wq, wk, wv, wo, fw1, fw2, qkvT,
                                          woT, fw1T, fw2T);
    // fused QKV: N=768, bf16 head-major split-output into q/k/v buffers
    gemm_mfma<256, false, false, false, 3><<<dim3(6, 256), 256, 0, stream>>>(
        xb16, qkvT, nullptr, nullptr, nullptr, qkv16, 256);
    // MFMA flash attention (head-major QKV) -> bf16 ctx (into xb16 region)
    attn_mfma<<<Bc * NHc, 256, 0, stream>>>(qkv16, qkv16 + 16777216,
                                            qkv16 + 33554432, code_mask, xb16);
    // x += ctx @ wo  (fp32 resid out to xbuf, bf16 copy to xq16)
    gemm_mfma<256, false, false, true, 2><<<dim3(2, 256), 256, 0, stream>>>(
        xb16, woT, nullptr, xbuf, xbuf, xq16, 256);
    // FFN (split pair: best-measured config; hid16 is L3-resident)
    gemm_mfma<256, true, true, false, 1><<<dim3(8, 256), 256, 0, stream>>>(
        xq16, fw1T, fb1, nullptr, nullptr, hid16, 1024);
    gemm_mfma<1024, true, false, true, 0><<<dim3(2, 256), 256, 0, stream>>>(
        hid16, fw2T, fb2, xbuf, final_out, nullptr, 256);
  };

  // 2) visit stream
  gather_both<<<8192, 256, 0, stream>>>(input_ids,
                                        (const float4*)embed_inputs_w,
                                        (float4*)xbuf, xb16);
  run_encoder((const float*)d_in[13], (const float*)d_in[14],
              (const float*)d_in[15], (const float*)d_in[16],
              (const float*)d_in[17], (const float*)d_in[18],
              (const float*)d_in[19], (const float*)d_in[20], out);

  // 3) dag stream
  gather_both<<<8192, 256, 0, stream>>>(input_ids, (const float4*)dict,
                                        (float4*)xbuf, xb16);
  run_encoder((const float*)d_in[21], (const float*)d_in[22],
              (const float*)d_in[23], (const float*)d_in[24],
              (const float*)d_in[25], (const float*)d_in[26],
              (const float*)d_in[27], (const float*)d_in[28], xbuf);

  pool_kernel<<<256, 512, 0, stream>>>(xbuf, code_mask, pool_w, pool_b,
                                       out + 8388608);
}